// Round 8
// baseline (290.640 us; speedup 1.0000x reference)
//
#include <hip/hip_runtime.h>
#include <math.h>

#define BB 8
#define CC 512
#define SS 1024
#define NHH 8
#define HDD 64
#define KD 512

typedef __attribute__((ext_vector_type(8))) short short8;
typedef __attribute__((ext_vector_type(4))) float f32x4;
typedef __attribute__((ext_vector_type(4))) unsigned short ushort4v;
typedef __attribute__((ext_vector_type(8))) unsigned short ushort8v;
typedef __attribute__((ext_vector_type(2))) unsigned int u32x2;

__device__ __forceinline__ unsigned short f2bf(float x) {
  union { float f; unsigned int u; } c; c.f = x;
  unsigned int r = (c.u + 0x7FFFu + ((c.u >> 16) & 1u)) >> 16;
  return (unsigned short)r;
}
__device__ __forceinline__ float b2f(unsigned short h) {
  union { unsigned int u; float f; } c; c.u = ((unsigned int)h) << 16; return c.f;
}

#define GLD_LDS(gp, lp) __builtin_amdgcn_global_load_lds( \
    (const __attribute__((address_space(1))) void*)(gp),  \
    (__attribute__((address_space(3))) void*)(lp), 16, 0, 0)

// ---------- block-wide sum over 256 threads (4 waves) ----------
__device__ __forceinline__ float block_reduce_sum(float v) {
  __shared__ float sm[4];
  #pragma unroll
  for (int o = 32; o > 0; o >>= 1) v += __shfl_down(v, o, 64);
  if ((threadIdx.x & 63) == 0) sm[threadIdx.x >> 6] = v;
  __syncthreads();
  float r = (sm[0] + sm[1]) + (sm[2] + sm[3]);
  __syncthreads();
  return r;
}

// ---------- LN1 apply + transpose: -> ln1 h/l + xs f32 (B,S,C) ---------------
__global__ __launch_bounds__(256) void ln1_apply(
    const float* __restrict__ x, const float2* __restrict__ mustd,
    const float* __restrict__ g, const float* __restrict__ be,
    unsigned short* __restrict__ yh, unsigned short* __restrict__ yl,
    float* __restrict__ xf) {
  __shared__ float tile[32][33];
  const int b = blockIdx.z, c0 = blockIdx.y * 32, s0 = blockIdx.x * 32;
  const int tx = threadIdx.x, ty = threadIdx.y;
  const float* xb = x + ((size_t)b * CC + c0) * SS + s0;
  #pragma unroll
  for (int i = ty; i < 32; i += 8)
    tile[i][tx] = xb[(size_t)i * SS + tx];
  __syncthreads();
  const float gc = g[c0 + tx], bc = be[c0 + tx];
  #pragma unroll
  for (int i = ty; i < 32; i += 8) {
    const float2 ms = mustd[b * SS + s0 + i];
    const float v = tile[tx][i];
    const float y = (v - ms.x) * ms.y * gc + bc;
    const size_t oi = ((size_t)b * SS + s0 + i) * CC + c0 + tx;
    const unsigned short hy = f2bf(y);
    yh[oi] = hy; yl[oi] = f2bf(y - b2f(hy));
    xf[oi] = v;
  }
}

// ---------- LayerNorm (C=512), one wave per row: no barriers, no LDS ---------
__global__ __launch_bounds__(256) void ln_bf16_k(const float* __restrict__ in,
                                                 const float* __restrict__ g,
                                                 const float* __restrict__ be,
                                                 unsigned short* __restrict__ outh) {
  const int wv = threadIdx.x >> 6, ln = threadIdx.x & 63;
  const size_t row = (size_t)blockIdx.x * 4 + wv;
  const float* r = in + row * CC + ln * 8;
  const float4 v0 = *(const float4*)(r);
  const float4 v1 = *(const float4*)(r + 4);
  float s = (v0.x + v0.y + v0.z + v0.w) + (v1.x + v1.y + v1.z + v1.w);
  #pragma unroll
  for (int o = 32; o > 0; o >>= 1) s += __shfl_xor(s, o, 64);
  const float mu = s * (1.0f / CC);
  float d[8] = {v0.x - mu, v0.y - mu, v0.z - mu, v0.w - mu,
                v1.x - mu, v1.y - mu, v1.z - mu, v1.w - mu};
  float q = 0.f;
  #pragma unroll
  for (int i = 0; i < 8; ++i) q += d[i] * d[i];
  #pragma unroll
  for (int o = 32; o > 0; o >>= 1) q += __shfl_xor(q, o, 64);
  const float rstd = rsqrtf(q * (1.0f / CC) + 1e-5f);
  const float4 g0 = *(const float4*)(g + ln * 8);
  const float4 g1 = *(const float4*)(g + ln * 8 + 4);
  const float4 b0 = *(const float4*)(be + ln * 8);
  const float4 b1 = *(const float4*)(be + ln * 8 + 4);
  const float gv[8] = {g0.x, g0.y, g0.z, g0.w, g1.x, g1.y, g1.z, g1.w};
  const float bv[8] = {b0.x, b0.y, b0.z, b0.w, b1.x, b1.y, b1.z, b1.w};
  ushort8v o8;
  #pragma unroll
  for (int i = 0; i < 8; ++i) o8[i] = f2bf(d[i] * rstd * gv[i] + bv[i]);
  *(ushort8v*)(outh + row * CC + ln * 8) = o8;
}

// ---------- weight convert + LN1 stats, one flat launch ----------------------
// blocks [0,1536): weight panels (as before); blocks [1536,1664): ln1 stats.
// Q_W / Q_b pre-scaled by 1/sqrt(512)*log2(e).
__global__ __launch_bounds__(256) void convert_and_stats(
    const float* __restrict__ QW, const float* __restrict__ KW,
    const float* __restrict__ VW, const float* __restrict__ OW,
    const float* __restrict__ W1, const float* __restrict__ W2,
    const float* __restrict__ Qb, const float* __restrict__ Kb,
    const float* __restrict__ Vb,
    unsigned short* __restrict__ BtQKh, unsigned short* __restrict__ BtQKl,
    unsigned short* __restrict__ BtVh,
    unsigned short* __restrict__ BtOh, unsigned short* __restrict__ BtOl,
    unsigned short* __restrict__ BtW1h, unsigned short* __restrict__ BtW2h,
    float* __restrict__ qkvb,
    const float* __restrict__ x, float2* __restrict__ mustd) {
  const int bid = blockIdx.x;
  if (bid < 1536) {
    const float SCL = 0.044194173824159216f * 1.4426950408889634f;
    __shared__ float tile[32][33];
    const int bx = bid & 15, by = (bid >> 4) & 1, p = bid >> 5;
    const int wsel = p >> 3, sub = p & 7;
    const int k0 = bx * 32, d0 = by * 32;
    const int tx = threadIdx.x & 31, ty = threadIdx.x >> 5;
    const float* w; int rs; unsigned short *dh, *dl; int nbase; float mul = 1.0f;
    switch (wsel) {
      case 0:  w = QW + sub * 32768; rs = 64;  dh = BtQKh; dl = BtQKl;  nbase = sub * 64; mul = SCL; break;
      case 1:  w = KW + sub * 32768; rs = 64;  dh = BtQKh; dl = BtQKl;  nbase = 512 + sub * 64;  break;
      case 2:  w = VW + sub * 32768; rs = 64;  dh = BtVh;  dl = nullptr; nbase = sub * 64;       break;
      case 3:  w = OW + sub * 64;    rs = 512; dh = BtOh;  dl = BtOl;   nbase = sub * 64;        break;
      case 4:  w = W1 + sub * 64;    rs = 512; dh = BtW1h; dl = nullptr; nbase = sub * 64;       break;
      default: w = W2 + sub * 64;    rs = 512; dh = BtW2h; dl = nullptr; nbase = sub * 64;       break;
    }
    for (int i = ty; i < 32; i += 8)
      tile[i][tx] = w[(size_t)(k0 + i) * rs + d0 + tx];
    __syncthreads();
    for (int i = ty; i < 32; i += 8) {
      float f = tile[tx][i] * mul;
      unsigned short h = f2bf(f);
      size_t idx = (size_t)(nbase + d0 + i) * KD + k0 + tx;
      dh[idx] = h;
      if (dl) dl[idx] = f2bf(f - b2f(h));
    }
    if (bid == 0) {
      int t = threadIdx.x;
      for (int i = t; i < 1536; i += 256)
        qkvb[i] = i < 512 ? Qb[i] * SCL : (i < 1024 ? Kb[i - 512] : Vb[i - 1024]);
    }
  } else {
    const int bid2 = bid - 1536;
    const int b = bid2 >> 4, s0 = (bid2 & 15) * 64;
    const int sl = threadIdx.x & 63, cg = threadIdx.x >> 6;
    const float* xp = x + (size_t)b * CC * SS + s0 + sl;
    float ps = 0.f, pq = 0.f;
    #pragma unroll 8
    for (int i = 0; i < 128; ++i) {
      const float v = xp[(size_t)(cg * 128 + i) * SS];
      ps += v; pq += v * v;
    }
    __shared__ float sred[2][4][64];
    sred[0][cg][sl] = ps; sred[1][cg][sl] = pq;
    __syncthreads();
    if (cg == 0) {
      const float s = (sred[0][0][sl] + sred[0][1][sl]) + (sred[0][2][sl] + sred[0][3][sl]);
      const float q = (sred[1][0][sl] + sred[1][1][sl]) + (sred[1][2][sl] + sred[1][3][sl]);
      const float mu = s * (1.0f / CC);
      const float rs = rsqrtf(q * (1.0f / CC) - mu * mu + 1e-5f);
      mustd[b * SS + s0 + sl] = make_float2(mu, rs);
    }
  }
}

// ---------- fused QKV projection GEMM, 128x128 tiles, XCD-swizzled grid ------
__global__ __launch_bounds__(256) void gemm_qkv(
    const unsigned short* __restrict__ Ah, const unsigned short* __restrict__ Al,
    const unsigned short* __restrict__ Bth, const unsigned short* __restrict__ Btl,
    const float* __restrict__ bias,
    unsigned short* __restrict__ qkh, unsigned short* __restrict__ qkl,
    unsigned short* __restrict__ vt) {
  __shared__ __align__(16) unsigned short smem[4 * 128 * 32];
  unsigned short* As = smem;
  unsigned short* Bs = smem + 2 * 128 * 32;
  const int tid = threadIdx.x;
  const int w = tid >> 6, l = tid & 63, quad = l >> 4, lm = l & 15;
  const int f = blockIdx.x, xcd = f & 7, gidx = f >> 3;
  const int n0 = (gidx >> 3) * 128;
  const int m0 = (((gidx & 7) << 3) | xcd) * 128;
  const bool splitB = n0 < 1024;
  const int wm = (w >> 1) * 64, wn = (w & 1) * 64;
  const int srow = tid >> 2;
  const int sch = (((tid & 3) ^ (srow & 3)) * 8);
  const unsigned short* Agh = Ah + (size_t)(m0 + srow) * KD + sch;
  const unsigned short* Agl = Al + (size_t)(m0 + srow) * KD + sch;
  const unsigned short* Bgh = Bth + (size_t)(n0 + srow) * KD + sch;
  const unsigned short* Bgl = Btl + (size_t)(n0 + srow) * KD + sch;
  unsigned short* Aswh = As + w * 512;
  unsigned short* Aswl = As + 4096 + w * 512;
  unsigned short* Bswh = Bs + w * 512;
  unsigned short* Bswl = Bs + 4096 + w * 512;
  const int rch = ((quad ^ (lm & 3)) * 8);
  const f32x4 fzero = {0.f, 0.f, 0.f, 0.f};
  f32x4 acc[4][4];
  #pragma unroll
  for (int i = 0; i < 4; ++i)
    #pragma unroll
    for (int j = 0; j < 4; ++j) acc[i][j] = fzero;
  for (int k0 = 0; k0 < KD; k0 += 32) {
    __syncthreads();
    GLD_LDS(Agh + k0, Aswh);
    GLD_LDS(Agh + k0 + 64 * KD, Aswh + 2048);
    GLD_LDS(Agl + k0, Aswl);
    GLD_LDS(Agl + k0 + 64 * KD, Aswl + 2048);
    GLD_LDS(Bgh + k0, Bswh);
    GLD_LDS(Bgh + k0 + 64 * KD, Bswh + 2048);
    if (splitB) {
      GLD_LDS(Bgl + k0, Bswl);
      GLD_LDS(Bgl + k0 + 64 * KD, Bswl + 2048);
    }
    __syncthreads();
    short8 afh[4], afl[4], bfh[4], bfl[4];
    #pragma unroll
    for (int i = 0; i < 4; ++i) {
      afh[i] = *(const short8*)(As + (wm + i * 16 + lm) * 32 + rch);
      afl[i] = *(const short8*)(As + 4096 + (wm + i * 16 + lm) * 32 + rch);
    }
    #pragma unroll
    for (int j = 0; j < 4; ++j)
      bfh[j] = *(const short8*)(Bs + (wn + j * 16 + lm) * 32 + rch);
    if (splitB) {
      #pragma unroll
      for (int j = 0; j < 4; ++j)
        bfl[j] = *(const short8*)(Bs + 4096 + (wn + j * 16 + lm) * 32 + rch);
      #pragma unroll
      for (int i = 0; i < 4; ++i)
        #pragma unroll
        for (int j = 0; j < 4; ++j) {
          f32x4 t = acc[i][j];
          t = __builtin_amdgcn_mfma_f32_16x16x32_bf16(afh[i], bfh[j], t, 0, 0, 0);
          t = __builtin_amdgcn_mfma_f32_16x16x32_bf16(afh[i], bfl[j], t, 0, 0, 0);
          t = __builtin_amdgcn_mfma_f32_16x16x32_bf16(afl[i], bfh[j], t, 0, 0, 0);
          acc[i][j] = t;
        }
    } else {
      #pragma unroll
      for (int i = 0; i < 4; ++i)
        #pragma unroll
        for (int j = 0; j < 4; ++j)
          acc[i][j] = __builtin_amdgcn_mfma_f32_16x16x32_bf16(afh[i], bfh[j], acc[i][j], 0, 0, 0);
    }
  }
  if (splitB) {
    #pragma unroll
    for (int i = 0; i < 4; ++i) {
      const int row = m0 + wm + i * 16 + quad * 4;
      #pragma unroll
      for (int j = 0; j < 4; ++j) {
        const int ncol = n0 + wn + j * 16 + lm;
        const float bv = bias[ncol];
        #pragma unroll
        for (int r = 0; r < 4; ++r) {
          const float xv = acc[i][j][r] + bv;
          const size_t oi = (size_t)(row + r) * 1024 + ncol;
          unsigned short h = f2bf(xv);
          qkh[oi] = h;
          qkl[oi] = f2bf(xv - b2f(h));
        }
      }
    }
  } else {
    __syncthreads();
    #pragma unroll
    for (int i = 0; i < 4; ++i) {
      const int mlb = wm + i * 16 + quad * 4;
      #pragma unroll
      for (int j = 0; j < 4; ++j) {
        const int nl = wn + j * 16 + lm;
        const float bv = bias[n0 + nl];
        ushort4v pk;
        #pragma unroll
        for (int r = 0; r < 4; ++r) pk[r] = f2bf(acc[i][j][r] + bv);
        const int chunk = ((mlb >> 3) ^ (nl & 15));
        *(ushort4v*)(smem + nl * 128 + chunk * 8 + (mlb & 7)) = pk;
      }
    }
    __syncthreads();
    const int tn = tid >> 4, tc = tid & 15;
    const int bb2 = m0 >> 10, sbase = m0 & 1023;
    #pragma unroll
    for (int pass = 0; pass < 8; ++pass) {
      const int nl = pass * 16 + tn;
      const int hh = (n0 - 1024 + nl) >> 6, dd = nl & 63;
      short8 v8 = *(const short8*)(smem + nl * 128 + ((tc ^ (nl & 15)) * 8));
      *(short8*)(vt + ((size_t)(bb2 * 8 + hh) * 64 + dd) * 1024 + sbase + tc * 8) = v8;
    }
  }
}

// ---------- 64x64-tile GEMM, BK=64, GLD staging, XCD-swizzled grid -----------
template<int SB, int GELU, int OUTMODE, int RESID, int TRANS>
__global__ __launch_bounds__(256) void gemm64(
    const unsigned short* __restrict__ Ah,
    const unsigned short* __restrict__ Bh, const unsigned short* __restrict__ Bl,
    const float* __restrict__ bias, const float* __restrict__ residf,
    const unsigned short* __restrict__ residh, const unsigned short* __restrict__ residl,
    unsigned short* __restrict__ outh, float* __restrict__ outf, int ldc) {
  constexpr int STAGE = (SB ? 3 : 2) * 8192;
  constexpr int TSIZE = TRANS ? 64 * 65 * 4 : 0;
  __shared__ __align__(16) unsigned char smem[STAGE > TSIZE ? STAGE : TSIZE];
  unsigned short* As  = (unsigned short*)smem;
  unsigned short* Bs  = (unsigned short*)(smem + 8192);
  unsigned short* Bls = (unsigned short*)(smem + 16384);
  float (*ttile)[65]  = (float(*)[65])smem;
  const int tid = threadIdx.x;
  const int w = tid >> 6, l = tid & 63, quad = l >> 4, lm = l & 15;
  const int f = blockIdx.x, xcd = f & 7, gidx = f >> 3;
  const int n0 = (gidx >> 4) * 64;
  const int m0 = (((gidx & 15) << 3) | xcd) * 64;
  const int wm = (w >> 1) * 32, wn = (w & 1) * 32;
  const int srow8 = tid >> 3;
  const int sch8  = ((tid & 7) ^ (srow8 & 7)) * 8;
  const unsigned short* Ag  = Ah + (size_t)(m0 + srow8) * KD + sch8;
  const unsigned short* Bg  = Bh + (size_t)(n0 + srow8) * KD + sch8;
  const unsigned short* Bgl = SB ? Bl + (size_t)(n0 + srow8) * KD + sch8 : nullptr;
  const f32x4 fzero = {0.f, 0.f, 0.f, 0.f};
  f32x4 acc[2][2];
  #pragma unroll
  for (int i = 0; i < 2; ++i)
    #pragma unroll
    for (int j = 0; j < 2; ++j) acc[i][j] = fzero;
  for (int k0 = 0; k0 < KD; k0 += 64) {
    __syncthreads();
    GLD_LDS(Ag + k0, As + w * 512);
    GLD_LDS(Ag + k0 + 32 * KD, As + 2048 + w * 512);
    GLD_LDS(Bg + k0, Bs + w * 512);
    GLD_LDS(Bg + k0 + 32 * KD, Bs + 2048 + w * 512);
    if constexpr (SB) {
      GLD_LDS(Bgl + k0, Bls + w * 512);
      GLD_LDS(Bgl + k0 + 32 * KD, Bls + 2048 + w * 512);
    }
    __syncthreads();
    #pragma unroll
    for (int ks = 0; ks < 2; ++ks) {
      const int kc = ((ks * 4 + quad) ^ (lm & 7)) * 8;
      short8 af[2], bfh[2], bfl[2];
      #pragma unroll
      for (int i = 0; i < 2; ++i)
        af[i] = *(const short8*)(As + (wm + i * 16 + lm) * 64 + kc);
      #pragma unroll
      for (int j = 0; j < 2; ++j)
        bfh[j] = *(const short8*)(Bs + (wn + j * 16 + lm) * 64 + kc);
      if constexpr (SB) {
        #pragma unroll
        for (int j = 0; j < 2; ++j)
          bfl[j] = *(const short8*)(Bls + (wn + j * 16 + lm) * 64 + kc);
      }
      #pragma unroll
      for (int i = 0; i < 2; ++i)
        #pragma unroll
        for (int j = 0; j < 2; ++j) {
          f32x4 t = acc[i][j];
          t = __builtin_amdgcn_mfma_f32_16x16x32_bf16(af[i], bfh[j], t, 0, 0, 0);
          if constexpr (SB)
            t = __builtin_amdgcn_mfma_f32_16x16x32_bf16(af[i], bfl[j], t, 0, 0, 0);
          acc[i][j] = t;
        }
    }
  }
  if constexpr (TRANS) __syncthreads();
  #pragma unroll
  for (int i = 0; i < 2; ++i) {
    const int row = m0 + wm + i * 16 + quad * 4;
    #pragma unroll
    for (int j = 0; j < 2; ++j) {
      const int col = n0 + wn + j * 16 + lm;
      const float bv = bias[col];
      #pragma unroll
      for (int r = 0; r < 4; ++r) {
        float x = acc[i][j][r] + bv;
        if (GELU) x = 0.5f * x * (1.0f + erff(x * 0.70710678118654752f));
        const size_t ri = (size_t)(row + r) * CC + col;
        if (RESID == 1) x += residf[ri];
        if (RESID == 2) x += b2f(residh[ri]) + b2f(residl[ri]);
        if constexpr (TRANS) {
          ttile[wm + i * 16 + quad * 4 + r][wn + j * 16 + lm] = x;
        } else {
          const size_t oi = (size_t)(row + r) * ldc + col;
          if (OUTMODE == 0) outf[oi] = x;
          else outh[oi] = f2bf(x);
        }
      }
    }
  }
  if constexpr (TRANS) {
    __syncthreads();
    const int bi = m0 >> 10, s0 = m0 & 1023;
    const int s = tid & 63;
    #pragma unroll
    for (int c0 = 0; c0 < 64; c0 += 4) {
      const int col = c0 + (tid >> 6);
      outf[(size_t)(bi * 512 + n0 + col) * 1024 + s0 + s] = ttile[s][col];
    }
  }
}

// ---------- flash attention: swapped QK^T, K staged in LDS, V direct-from-L2 -
// S^T = mfma(K, Q): lane (quad,lm) holds q=lm, k = j*16+quad*4+r  (16 k per lane)
// V (8KB/tile, L2-resident, 4-wave L1 reuse) is loaded straight to registers
// at loop top -> latency covered by K ds_write + barrier + QK^T MFMAs (m169).
__global__ __launch_bounds__(256) void attn_mfma(
    const unsigned short* __restrict__ QKh, const unsigned short* __restrict__ QKl,
    const unsigned short* __restrict__ Vt, unsigned short* __restrict__ Oh) {
  __shared__ __align__(16) unsigned short Ksh[64 * 64], Ksl[64 * 64];
  __shared__ __align__(16) unsigned short Pts[4][16 * 64];
  const int f = blockIdx.x, xcd = f & 7, gidx = f >> 3;
  const int bh = (xcd << 3) | (gidx >> 4);
  const int q0 = (gidx & 15) * 64, h = bh & 7, b = bh >> 3;
  const int tid = threadIdx.x, w = tid >> 6, l = tid & 63, quad = l >> 4, lm = l & 15;
  const int LDQ = 2 * CC;
  const size_t qkbase = (size_t)b * SS * LDQ;
  const int srow8 = tid >> 3;
  const int sch8  = ((tid & 7) ^ (srow8 & 7)) * 8;
  const unsigned short* Vrow = Vt + (size_t)(b * 8 + h) * 64 * 1024;
  const unsigned short* kgh = QKh + qkbase + (size_t)srow8 * LDQ + CC + h * 64 + sch8;
  const unsigned short* kgl = QKl + qkbase + (size_t)srow8 * LDQ + CC + h * 64 + sch8;
  const int lofs = w * 512 + l * 8;   // per-lane LDS slot (shorts), 16B stride
  short8 qh[2], ql[2];
  {
    const size_t qo = qkbase + (size_t)(q0 + w * 16 + lm) * LDQ + h * 64 + quad * 8;
    qh[0] = *(const short8*)(QKh + qo);
    qh[1] = *(const short8*)(QKh + qo + 32);
    ql[0] = *(const short8*)(QKl + qo);
    ql[1] = *(const short8*)(QKl + qo + 32);
  }
  const f32x4 fzero = {0.f, 0.f, 0.f, 0.f};
  float m = -1e30f, lsum = 0.f;
  f32x4 oacc[4];
  #pragma unroll
  for (int j = 0; j < 4; ++j) oacc[j] = fzero;
  unsigned char* Pb = (unsigned char*)(Pts[w]);
  const int pwbase = lm * 128 + ((quad & 1) << 3);
  const int prbase = lm * 128;
  // prologue: prefetch K tile 0 into registers
  short8 s0h = *(const short8*)(kgh);
  short8 s1h = *(const short8*)(kgh + (size_t)32 * LDQ);
  short8 s0l = *(const short8*)(kgl);
  short8 s1l = *(const short8*)(kgl + (size_t)32 * LDQ);
  for (int kt = 0; kt < SS; kt += 64) {
    // V fragments for THIS tile: direct global->reg, issued before the
    // barrier so the whole K-write + QK^T phase covers their latency.
    short8 vvr[2][4];
    #pragma unroll
    for (int st = 0; st < 2; ++st)
      #pragma unroll
      for (int j = 0; j < 4; ++j)
        vvr[st][j] = *(const short8*)(
            Vrow + (size_t)(j * 16 + lm) * 1024 + kt + (st * 4 + quad) * 8);
    __syncthreads();                     // all waves done reading prev K tile
    *(short8*)(Ksh + lofs)        = s0h; // vmcnt drain lands here (covered)
    *(short8*)(Ksh + 2048 + lofs) = s1h;
    *(short8*)(Ksl + lofs)        = s0l;
    *(short8*)(Ksl + 2048 + lofs) = s1l;
    __syncthreads();                     // writes visible
    {                                    // issue next K tile's loads (hidden)
      const int ktn = (kt + 64) & (SS - 1);
      s0h = *(const short8*)(kgh + (size_t)ktn * LDQ);
      s1h = *(const short8*)(kgh + (size_t)(ktn + 32) * LDQ);
      s0l = *(const short8*)(kgl + (size_t)ktn * LDQ);
      s1l = *(const short8*)(kgl + (size_t)(ktn + 32) * LDQ);
    }
    f32x4 sc[4];
    __builtin_amdgcn_s_setprio(1);
    {  // st = 0 : A = K fragment, B = Q fragment  ->  S^T
      const int kc = (quad ^ (lm & 7)) * 8;
      #pragma unroll
      for (int j = 0; j < 4; ++j) {
        short8 kh = *(const short8*)(Ksh + (j * 16 + lm) * 64 + kc);
        short8 kl = *(const short8*)(Ksl + (j * 16 + lm) * 64 + kc);
        f32x4 t = __builtin_amdgcn_mfma_f32_16x16x32_bf16(kh, qh[0], fzero, 0, 0, 0);
        t = __builtin_amdgcn_mfma_f32_16x16x32_bf16(kl, qh[0], t, 0, 0, 0);
        t = __builtin_amdgcn_mfma_f32_16x16x32_bf16(kh, ql[0], t, 0, 0, 0);
        sc[j] = t;
      }
    }
    {  // st = 1
      const int kc = ((4 + quad) ^ (lm & 7)) * 8;
      #pragma unroll
      for (int j = 0; j < 4; ++j) {
        short8 kh = *(const short8*)(Ksh + (j * 16 + lm) * 64 + kc);
        short8 kl = *(const short8*)(Ksl + (j * 16 + lm) * 64 + kc);
        f32x4 t = sc[j];
        t = __builtin_amdgcn_mfma_f32_16x16x32_bf16(kh, qh[1], t, 0, 0, 0);
        t = __builtin_amdgcn_mfma_f32_16x16x32_bf16(kl, qh[1], t, 0, 0, 0);
        t = __builtin_amdgcn_mfma_f32_16x16x32_bf16(kh, ql[1], t, 0, 0, 0);
        sc[j] = t;
      }
    }
    __builtin_amdgcn_s_setprio(0);
    // lane-local max over 16 k + cross-quad butterfly (2 shfl)
    float mt0 = fmaxf(fmaxf(sc[0][0], sc[0][1]), fmaxf(sc[0][2], sc[0][3]));
    float mt1 = fmaxf(fmaxf(sc[1][0], sc[1][1]), fmaxf(sc[1][2], sc[1][3]));
    float mt2 = fmaxf(fmaxf(sc[2][0], sc[2][1]), fmaxf(sc[2][2], sc[2][3]));
    float mt3 = fmaxf(fmaxf(sc[3][0], sc[3][1]), fmaxf(sc[3][2], sc[3][3]));
    float mt = fmaxf(fmaxf(mt0, mt1), fmaxf(mt2, mt3));
    mt = fmaxf(mt, __shfl_xor(mt, 16, 64));
    mt = fmaxf(mt, __shfl_xor(mt, 32, 64));
    // T13 defer-max: rescale only when the max jumps by > 8 (P stays <= 2^8,
    // bf16 truncation error is relative, lsum-normalization cancels the scale)
    if (__any(mt > m + 8.f)) {
      const float mnew = fmaxf(m, mt);
      const float alpha = exp2f(m - mnew);
      m = mnew;
      lsum *= alpha;
      #pragma unroll
      for (int j = 0; j < 4; ++j)
        #pragma unroll
        for (int r = 0; r < 4; ++r) oacc[j][r] *= alpha;
    }
    float ls = 0.f;
    #pragma unroll
    for (int j = 0; j < 4; ++j)
      #pragma unroll
      for (int r = 0; r < 4; ++r) {
        sc[j][r] = exp2f(sc[j][r] - m);
        ls += sc[j][r];
      }
    ls += __shfl_xor(ls, 16, 64);
    ls += __shfl_xor(ls, 32, 64);
    lsum += ls;
    // pack P^T: per j, 4 k-contiguous bf16 (truncated) -> one b64 LDS write
    #pragma unroll
    for (int j = 0; j < 4; ++j) {
      union { float f; unsigned int u; } c0, c1, c2, c3;
      c0.f = sc[j][0]; c1.f = sc[j][1]; c2.f = sc[j][2]; c3.f = sc[j][3];
      u32x2 pk;
      pk[0] = __builtin_amdgcn_perm(c1.u, c0.u, 0x07060302u);  // [bf(s0)|bf(s1)]
      pk[1] = __builtin_amdgcn_perm(c3.u, c2.u, 0x07060302u);  // [bf(s2)|bf(s3)]
      const int slot = ((j << 1) | (quad >> 1)) ^ (lm & 7);
      *(u32x2*)(Pb + pwbase + (slot << 4)) = pk;
    }
    // PV: O^T += V^T-frag (regs) x P^T-frag
    __builtin_amdgcn_s_setprio(1);
    #pragma unroll
    for (int st = 0; st < 2; ++st) {
      short8 pf = *(const short8*)(Pb + prbase + ((((st << 2) | quad) ^ (lm & 7)) << 4));
      #pragma unroll
      for (int j = 0; j < 4; ++j)
        oacc[j] = __builtin_amdgcn_mfma_f32_16x16x32_bf16(vvr[st][j], pf, oacc[j], 0, 0, 0);
    }
    __builtin_amdgcn_s_setprio(0);
  }
  const float inv = 1.f / lsum;
  // lane holds O[q=lm][d = j*16 + quad*4 + r] -> 4x 8B stores
  const size_t obase =
      (size_t)b * SS * CC + (size_t)(q0 + w * 16 + lm) * CC + h * 64 + quad * 4;
  #pragma unroll
  for (int j = 0; j < 4; ++j) {
    ushort4v pk;
    #pragma unroll
    for (int r = 0; r < 4; ++r) pk[r] = f2bf(oacc[j][r] * inv);
    *(ushort4v*)(Oh + obase + j * 16) = pk;
  }
}

extern "C" void kernel_launch(void* const* d_in, const int* in_sizes, int n_in,
                              void* d_out, int out_size, void* d_ws, size_t ws_size,
                              hipStream_t stream) {
  const float* x    = (const float*)d_in[0];
  const float* K_W  = (const float*)d_in[2];
  const float* K_b  = (const float*)d_in[3];
  const float* Q_W  = (const float*)d_in[4];
  const float* Q_b  = (const float*)d_in[5];
  const float* V_W  = (const float*)d_in[6];
  const float* V_b  = (const float*)d_in[7];
  const float* O_W  = (const float*)d_in[8];
  const float* O_b  = (const float*)d_in[9];
  const float* ln1g = (const float*)d_in[10];
  const float* ln1b = (const float*)d_in[11];
  const float* ln2g = (const float*)d_in[12];
  const float* ln2b = (const float*)d_in[13];
  const float* W1   = (const float*)d_in[14];
  const float* b1   = (const float*)d_in[15];
  const float* W2   = (const float*)d_in[16];
  const float* b2   = (const float*)d_in[17];
  float* out = (float*)d_out;

  unsigned char* ws = (unsigned char*)d_ws;
  const size_t MB = 1u << 20;
  unsigned short* qkh   = (unsigned short*)(ws);             // (B,S,1024) 16MB
  unsigned short* qkl   = (unsigned short*)(ws + 16 * MB);   // 16MB
  unsigned short* vt    = (unsigned short*)(ws + 32 * MB);   // (B,NH,HD,S) 8MB
  unsigned short* ln1h  = (unsigned short*)(ws + 40 * MB);   // 8MB
  unsigned short* ln1l  = (unsigned short*)(ws + 48 * MB);   // 8MB
  float* xsf            = (float*)(ws + 56 * MB);            // (B,S,C) f32 16MB
  unsigned short* oh    = ln1h;
  float* out1           = (float*)(ws + 72 * MB);            // 16MB
  unsigned short* ln2h  = qkh;
  unsigned short* geluh = (unsigned short*)(ws + 8 * MB);
  unsigned short* BtAll = (unsigned short*)(ws + 88 * MB);
  unsigned short* BtQKh = BtAll;
  unsigned short* BtVh  = BtAll + 1024 * 512;
  unsigned short* BtQKl = BtVh + 512 * 512;
  unsigned short* BtOh  = BtQKl + 1024 * 512;
  unsigned short* BtOl  = BtOh + 512 * 512;
  unsigned short* BtW1h = BtOl + 512 * 512;
  unsigned short* BtW2h = BtW1h + 512 * 512;
  float* qkvb           = (float*)(BtW2h + 512 * 512);
  float2* mustd         = (float2*)(ws + 96 * MB);

  dim3 tb32(32, 8);
  convert_and_stats<<<1536 + 128, 256, 0, stream>>>(
      Q_W, K_W, V_W, O_W, W1, W2, Q_b, K_b, V_b,
      BtQKh, BtQKl, BtVh, BtOh, BtOl, BtW1h, BtW2h, qkvb, x, mustd);
  ln1_apply<<<dim3(SS / 32, CC / 32, BB), tb32, 0, stream>>>(
      x, mustd, ln1g, ln1b, ln1h, ln1l, xsf);
  gemm_qkv<<<768, 256, 0, stream>>>(
      ln1h, ln1l, BtAll, BtQKl, qkvb, qkh, qkl, vt);
  attn_mfma<<<1024, 256, 0, stream>>>(qkh, qkl, vt, oh);
  gemm64<1, 0, 0, 1, 0><<<1024, 256, 0, stream>>>(
      oh, BtOh, BtOl, O_b, xsf, nullptr, nullptr, nullptr, out1, CC);
  ln_bf16_k<<<BB * SS / 4, 256, 0, stream>>>(out1, ln2g, ln2b, ln2h);
  gemm64<0, 1, 1, 0, 0><<<1024, 256, 0, stream>>>(
      ln2h, BtW1h, nullptr, b1, nullptr, nullptr, nullptr, geluh, nullptr, CC);
  gemm64<0, 0, 0, 1, 1><<<1024, 256, 0, stream>>>(
      geluh, BtW2h, nullptr, b2, out1, nullptr, nullptr, nullptr, out, CC);
}

// Round 9
// 266.951 us; speedup vs baseline: 1.0887x; 1.0887x over previous
//
#include <hip/hip_runtime.h>
#include <math.h>

#define BB 8
#define CC 512
#define SS 1024
#define NHH 8
#define HDD 64
#define KD 512

typedef __attribute__((ext_vector_type(8))) short short8;
typedef __attribute__((ext_vector_type(4))) float f32x4;
typedef __attribute__((ext_vector_type(4))) unsigned short ushort4v;
typedef __attribute__((ext_vector_type(8))) unsigned short ushort8v;
typedef __attribute__((ext_vector_type(2))) unsigned int u32x2;

__device__ __forceinline__ unsigned short f2bf(float x) {
  union { float f; unsigned int u; } c; c.f = x;
  unsigned int r = (c.u + 0x7FFFu + ((c.u >> 16) & 1u)) >> 16;
  return (unsigned short)r;
}
__device__ __forceinline__ float b2f(unsigned short h) {
  union { unsigned int u; float f; } c; c.u = ((unsigned int)h) << 16; return c.f;
}

#define GLD_LDS(gp, lp) __builtin_amdgcn_global_load_lds( \
    (const __attribute__((address_space(1))) void*)(gp),  \
    (__attribute__((address_space(3))) void*)(lp), 16, 0, 0)

// ---------- block-wide sum over 256 threads (4 waves) ----------
__device__ __forceinline__ float block_reduce_sum(float v) {
  __shared__ float sm[4];
  #pragma unroll
  for (int o = 32; o > 0; o >>= 1) v += __shfl_down(v, o, 64);
  if ((threadIdx.x & 63) == 0) sm[threadIdx.x >> 6] = v;
  __syncthreads();
  float r = (sm[0] + sm[1]) + (sm[2] + sm[3]);
  __syncthreads();
  return r;
}

// ---------- LN1 apply + transpose: -> ln1 h/l + xs f32 (B,S,C) ---------------
__global__ __launch_bounds__(256) void ln1_apply(
    const float* __restrict__ x, const float2* __restrict__ mustd,
    const float* __restrict__ g, const float* __restrict__ be,
    unsigned short* __restrict__ yh, unsigned short* __restrict__ yl,
    float* __restrict__ xf) {
  __shared__ float tile[32][33];
  const int b = blockIdx.z, c0 = blockIdx.y * 32, s0 = blockIdx.x * 32;
  const int tx = threadIdx.x, ty = threadIdx.y;
  const float* xb = x + ((size_t)b * CC + c0) * SS + s0;
  #pragma unroll
  for (int i = ty; i < 32; i += 8)
    tile[i][tx] = xb[(size_t)i * SS + tx];
  __syncthreads();
  const float gc = g[c0 + tx], bc = be[c0 + tx];
  #pragma unroll
  for (int i = ty; i < 32; i += 8) {
    const float2 ms = mustd[b * SS + s0 + i];
    const float v = tile[tx][i];
    const float y = (v - ms.x) * ms.y * gc + bc;
    const size_t oi = ((size_t)b * SS + s0 + i) * CC + c0 + tx;
    const unsigned short hy = f2bf(y);
    yh[oi] = hy; yl[oi] = f2bf(y - b2f(hy));
    xf[oi] = v;
  }
}

// ---------- LayerNorm (C=512), one wave per row: no barriers, no LDS ---------
__global__ __launch_bounds__(256) void ln_bf16_k(const float* __restrict__ in,
                                                 const float* __restrict__ g,
                                                 const float* __restrict__ be,
                                                 unsigned short* __restrict__ outh) {
  const int wv = threadIdx.x >> 6, ln = threadIdx.x & 63;
  const size_t row = (size_t)blockIdx.x * 4 + wv;
  const float* r = in + row * CC + ln * 8;
  const float4 v0 = *(const float4*)(r);
  const float4 v1 = *(const float4*)(r + 4);
  float s = (v0.x + v0.y + v0.z + v0.w) + (v1.x + v1.y + v1.z + v1.w);
  #pragma unroll
  for (int o = 32; o > 0; o >>= 1) s += __shfl_xor(s, o, 64);
  const float mu = s * (1.0f / CC);
  float d[8] = {v0.x - mu, v0.y - mu, v0.z - mu, v0.w - mu,
                v1.x - mu, v1.y - mu, v1.z - mu, v1.w - mu};
  float q = 0.f;
  #pragma unroll
  for (int i = 0; i < 8; ++i) q += d[i] * d[i];
  #pragma unroll
  for (int o = 32; o > 0; o >>= 1) q += __shfl_xor(q, o, 64);
  const float rstd = rsqrtf(q * (1.0f / CC) + 1e-5f);
  const float4 g0 = *(const float4*)(g + ln * 8);
  const float4 g1 = *(const float4*)(g + ln * 8 + 4);
  const float4 b0 = *(const float4*)(be + ln * 8);
  const float4 b1 = *(const float4*)(be + ln * 8 + 4);
  const float gv[8] = {g0.x, g0.y, g0.z, g0.w, g1.x, g1.y, g1.z, g1.w};
  const float bv[8] = {b0.x, b0.y, b0.z, b0.w, b1.x, b1.y, b1.z, b1.w};
  ushort8v o8;
  #pragma unroll
  for (int i = 0; i < 8; ++i) o8[i] = f2bf(d[i] * rstd * gv[i] + bv[i]);
  *(ushort8v*)(outh + row * CC + ln * 8) = o8;
}

// ---------- weight convert + LN1 stats, one flat launch ----------------------
// blocks [0,1536): weight panels (as before); blocks [1536,1664): ln1 stats.
// Q_W / Q_b pre-scaled by 1/sqrt(512)*log2(e).
__global__ __launch_bounds__(256) void convert_and_stats(
    const float* __restrict__ QW, const float* __restrict__ KW,
    const float* __restrict__ VW, const float* __restrict__ OW,
    const float* __restrict__ W1, const float* __restrict__ W2,
    const float* __restrict__ Qb, const float* __restrict__ Kb,
    const float* __restrict__ Vb,
    unsigned short* __restrict__ BtQKh, unsigned short* __restrict__ BtQKl,
    unsigned short* __restrict__ BtVh,
    unsigned short* __restrict__ BtOh, unsigned short* __restrict__ BtOl,
    unsigned short* __restrict__ BtW1h, unsigned short* __restrict__ BtW2h,
    float* __restrict__ qkvb,
    const float* __restrict__ x, float2* __restrict__ mustd) {
  const int bid = blockIdx.x;
  if (bid < 1536) {
    const float SCL = 0.044194173824159216f * 1.4426950408889634f;
    __shared__ float tile[32][33];
    const int bx = bid & 15, by = (bid >> 4) & 1, p = bid >> 5;
    const int wsel = p >> 3, sub = p & 7;
    const int k0 = bx * 32, d0 = by * 32;
    const int tx = threadIdx.x & 31, ty = threadIdx.x >> 5;
    const float* w; int rs; unsigned short *dh, *dl; int nbase; float mul = 1.0f;
    switch (wsel) {
      case 0:  w = QW + sub * 32768; rs = 64;  dh = BtQKh; dl = BtQKl;  nbase = sub * 64; mul = SCL; break;
      case 1:  w = KW + sub * 32768; rs = 64;  dh = BtQKh; dl = BtQKl;  nbase = 512 + sub * 64;  break;
      case 2:  w = VW + sub * 32768; rs = 64;  dh = BtVh;  dl = nullptr; nbase = sub * 64;       break;
      case 3:  w = OW + sub * 64;    rs = 512; dh = BtOh;  dl = BtOl;   nbase = sub * 64;        break;
      case 4:  w = W1 + sub * 64;    rs = 512; dh = BtW1h; dl = nullptr; nbase = sub * 64;       break;
      default: w = W2 + sub * 64;    rs = 512; dh = BtW2h; dl = nullptr; nbase = sub * 64;       break;
    }
    for (int i = ty; i < 32; i += 8)
      tile[i][tx] = w[(size_t)(k0 + i) * rs + d0 + tx];
    __syncthreads();
    for (int i = ty; i < 32; i += 8) {
      float f = tile[tx][i] * mul;
      unsigned short h = f2bf(f);
      size_t idx = (size_t)(nbase + d0 + i) * KD + k0 + tx;
      dh[idx] = h;
      if (dl) dl[idx] = f2bf(f - b2f(h));
    }
    if (bid == 0) {
      int t = threadIdx.x;
      for (int i = t; i < 1536; i += 256)
        qkvb[i] = i < 512 ? Qb[i] * SCL : (i < 1024 ? Kb[i - 512] : Vb[i - 1024]);
    }
  } else {
    const int bid2 = bid - 1536;
    const int b = bid2 >> 4, s0 = (bid2 & 15) * 64;
    const int sl = threadIdx.x & 63, cg = threadIdx.x >> 6;
    const float* xp = x + (size_t)b * CC * SS + s0 + sl;
    float ps = 0.f, pq = 0.f;
    #pragma unroll 8
    for (int i = 0; i < 128; ++i) {
      const float v = xp[(size_t)(cg * 128 + i) * SS];
      ps += v; pq += v * v;
    }
    __shared__ float sred[2][4][64];
    sred[0][cg][sl] = ps; sred[1][cg][sl] = pq;
    __syncthreads();
    if (cg == 0) {
      const float s = (sred[0][0][sl] + sred[0][1][sl]) + (sred[0][2][sl] + sred[0][3][sl]);
      const float q = (sred[1][0][sl] + sred[1][1][sl]) + (sred[1][2][sl] + sred[1][3][sl]);
      const float mu = s * (1.0f / CC);
      const float rs = rsqrtf(q * (1.0f / CC) - mu * mu + 1e-5f);
      mustd[b * SS + s0 + sl] = make_float2(mu, rs);
    }
  }
}

// ---------- fused QKV projection GEMM, 128x128 tiles, XCD-swizzled grid ------
__global__ __launch_bounds__(256) void gemm_qkv(
    const unsigned short* __restrict__ Ah, const unsigned short* __restrict__ Al,
    const unsigned short* __restrict__ Bth, const unsigned short* __restrict__ Btl,
    const float* __restrict__ bias,
    unsigned short* __restrict__ qkh, unsigned short* __restrict__ qkl,
    unsigned short* __restrict__ vt) {
  __shared__ __align__(16) unsigned short smem[4 * 128 * 32];
  unsigned short* As = smem;
  unsigned short* Bs = smem + 2 * 128 * 32;
  const int tid = threadIdx.x;
  const int w = tid >> 6, l = tid & 63, quad = l >> 4, lm = l & 15;
  const int f = blockIdx.x, xcd = f & 7, gidx = f >> 3;
  const int n0 = (gidx >> 3) * 128;
  const int m0 = (((gidx & 7) << 3) | xcd) * 128;
  const bool splitB = n0 < 1024;
  const int wm = (w >> 1) * 64, wn = (w & 1) * 64;
  const int srow = tid >> 2;
  const int sch = (((tid & 3) ^ (srow & 3)) * 8);
  const unsigned short* Agh = Ah + (size_t)(m0 + srow) * KD + sch;
  const unsigned short* Agl = Al + (size_t)(m0 + srow) * KD + sch;
  const unsigned short* Bgh = Bth + (size_t)(n0 + srow) * KD + sch;
  const unsigned short* Bgl = Btl + (size_t)(n0 + srow) * KD + sch;
  unsigned short* Aswh = As + w * 512;
  unsigned short* Aswl = As + 4096 + w * 512;
  unsigned short* Bswh = Bs + w * 512;
  unsigned short* Bswl = Bs + 4096 + w * 512;
  const int rch = ((quad ^ (lm & 3)) * 8);
  const f32x4 fzero = {0.f, 0.f, 0.f, 0.f};
  f32x4 acc[4][4];
  #pragma unroll
  for (int i = 0; i < 4; ++i)
    #pragma unroll
    for (int j = 0; j < 4; ++j) acc[i][j] = fzero;
  for (int k0 = 0; k0 < KD; k0 += 32) {
    __syncthreads();
    GLD_LDS(Agh + k0, Aswh);
    GLD_LDS(Agh + k0 + 64 * KD, Aswh + 2048);
    GLD_LDS(Agl + k0, Aswl);
    GLD_LDS(Agl + k0 + 64 * KD, Aswl + 2048);
    GLD_LDS(Bgh + k0, Bswh);
    GLD_LDS(Bgh + k0 + 64 * KD, Bswh + 2048);
    if (splitB) {
      GLD_LDS(Bgl + k0, Bswl);
      GLD_LDS(Bgl + k0 + 64 * KD, Bswl + 2048);
    }
    __syncthreads();
    short8 afh[4], afl[4], bfh[4], bfl[4];
    #pragma unroll
    for (int i = 0; i < 4; ++i) {
      afh[i] = *(const short8*)(As + (wm + i * 16 + lm) * 32 + rch);
      afl[i] = *(const short8*)(As + 4096 + (wm + i * 16 + lm) * 32 + rch);
    }
    #pragma unroll
    for (int j = 0; j < 4; ++j)
      bfh[j] = *(const short8*)(Bs + (wn + j * 16 + lm) * 32 + rch);
    if (splitB) {
      #pragma unroll
      for (int j = 0; j < 4; ++j)
        bfl[j] = *(const short8*)(Bs + 4096 + (wn + j * 16 + lm) * 32 + rch);
      #pragma unroll
      for (int i = 0; i < 4; ++i)
        #pragma unroll
        for (int j = 0; j < 4; ++j) {
          f32x4 t = acc[i][j];
          t = __builtin_amdgcn_mfma_f32_16x16x32_bf16(afh[i], bfh[j], t, 0, 0, 0);
          t = __builtin_amdgcn_mfma_f32_16x16x32_bf16(afh[i], bfl[j], t, 0, 0, 0);
          t = __builtin_amdgcn_mfma_f32_16x16x32_bf16(afl[i], bfh[j], t, 0, 0, 0);
          acc[i][j] = t;
        }
    } else {
      #pragma unroll
      for (int i = 0; i < 4; ++i)
        #pragma unroll
        for (int j = 0; j < 4; ++j)
          acc[i][j] = __builtin_amdgcn_mfma_f32_16x16x32_bf16(afh[i], bfh[j], acc[i][j], 0, 0, 0);
    }
  }
  if (splitB) {
    #pragma unroll
    for (int i = 0; i < 4; ++i) {
      const int row = m0 + wm + i * 16 + quad * 4;
      #pragma unroll
      for (int j = 0; j < 4; ++j) {
        const int ncol = n0 + wn + j * 16 + lm;
        const float bv = bias[ncol];
        #pragma unroll
        for (int r = 0; r < 4; ++r) {
          const float xv = acc[i][j][r] + bv;
          const size_t oi = (size_t)(row + r) * 1024 + ncol;
          unsigned short h = f2bf(xv);
          qkh[oi] = h;
          qkl[oi] = f2bf(xv - b2f(h));
        }
      }
    }
  } else {
    __syncthreads();
    #pragma unroll
    for (int i = 0; i < 4; ++i) {
      const int mlb = wm + i * 16 + quad * 4;
      #pragma unroll
      for (int j = 0; j < 4; ++j) {
        const int nl = wn + j * 16 + lm;
        const float bv = bias[n0 + nl];
        ushort4v pk;
        #pragma unroll
        for (int r = 0; r < 4; ++r) pk[r] = f2bf(acc[i][j][r] + bv);
        const int chunk = ((mlb >> 3) ^ (nl & 15));
        *(ushort4v*)(smem + nl * 128 + chunk * 8 + (mlb & 7)) = pk;
      }
    }
    __syncthreads();
    const int tn = tid >> 4, tc = tid & 15;
    const int bb2 = m0 >> 10, sbase = m0 & 1023;
    #pragma unroll
    for (int pass = 0; pass < 8; ++pass) {
      const int nl = pass * 16 + tn;
      const int hh = (n0 - 1024 + nl) >> 6, dd = nl & 63;
      short8 v8 = *(const short8*)(smem + nl * 128 + ((tc ^ (nl & 15)) * 8));
      *(short8*)(vt + ((size_t)(bb2 * 8 + hh) * 64 + dd) * 1024 + sbase + tc * 8) = v8;
    }
  }
}

// ---------- 64x64-tile GEMM, BK=64, GLD staging, XCD-swizzled grid -----------
template<int SB, int GELU, int OUTMODE, int RESID, int TRANS>
__global__ __launch_bounds__(256) void gemm64(
    const unsigned short* __restrict__ Ah,
    const unsigned short* __restrict__ Bh, const unsigned short* __restrict__ Bl,
    const float* __restrict__ bias, const float* __restrict__ residf,
    const unsigned short* __restrict__ residh, const unsigned short* __restrict__ residl,
    unsigned short* __restrict__ outh, float* __restrict__ outf, int ldc) {
  constexpr int STAGE = (SB ? 3 : 2) * 8192;
  constexpr int TSIZE = TRANS ? 64 * 65 * 4 : 0;
  __shared__ __align__(16) unsigned char smem[STAGE > TSIZE ? STAGE : TSIZE];
  unsigned short* As  = (unsigned short*)smem;
  unsigned short* Bs  = (unsigned short*)(smem + 8192);
  unsigned short* Bls = (unsigned short*)(smem + 16384);
  float (*ttile)[65]  = (float(*)[65])smem;
  const int tid = threadIdx.x;
  const int w = tid >> 6, l = tid & 63, quad = l >> 4, lm = l & 15;
  const int f = blockIdx.x, xcd = f & 7, gidx = f >> 3;
  const int n0 = (gidx >> 4) * 64;
  const int m0 = (((gidx & 15) << 3) | xcd) * 64;
  const int wm = (w >> 1) * 32, wn = (w & 1) * 32;
  const int srow8 = tid >> 3;
  const int sch8  = ((tid & 7) ^ (srow8 & 7)) * 8;
  const unsigned short* Ag  = Ah + (size_t)(m0 + srow8) * KD + sch8;
  const unsigned short* Bg  = Bh + (size_t)(n0 + srow8) * KD + sch8;
  const unsigned short* Bgl = SB ? Bl + (size_t)(n0 + srow8) * KD + sch8 : nullptr;
  const f32x4 fzero = {0.f, 0.f, 0.f, 0.f};
  f32x4 acc[2][2];
  #pragma unroll
  for (int i = 0; i < 2; ++i)
    #pragma unroll
    for (int j = 0; j < 2; ++j) acc[i][j] = fzero;
  for (int k0 = 0; k0 < KD; k0 += 64) {
    __syncthreads();
    GLD_LDS(Ag + k0, As + w * 512);
    GLD_LDS(Ag + k0 + 32 * KD, As + 2048 + w * 512);
    GLD_LDS(Bg + k0, Bs + w * 512);
    GLD_LDS(Bg + k0 + 32 * KD, Bs + 2048 + w * 512);
    if constexpr (SB) {
      GLD_LDS(Bgl + k0, Bls + w * 512);
      GLD_LDS(Bgl + k0 + 32 * KD, Bls + 2048 + w * 512);
    }
    __syncthreads();
    #pragma unroll
    for (int ks = 0; ks < 2; ++ks) {
      const int kc = ((ks * 4 + quad) ^ (lm & 7)) * 8;
      short8 af[2], bfh[2], bfl[2];
      #pragma unroll
      for (int i = 0; i < 2; ++i)
        af[i] = *(const short8*)(As + (wm + i * 16 + lm) * 64 + kc);
      #pragma unroll
      for (int j = 0; j < 2; ++j)
        bfh[j] = *(const short8*)(Bs + (wn + j * 16 + lm) * 64 + kc);
      if constexpr (SB) {
        #pragma unroll
        for (int j = 0; j < 2; ++j)
          bfl[j] = *(const short8*)(Bls + (wn + j * 16 + lm) * 64 + kc);
      }
      #pragma unroll
      for (int i = 0; i < 2; ++i)
        #pragma unroll
        for (int j = 0; j < 2; ++j) {
          f32x4 t = acc[i][j];
          t = __builtin_amdgcn_mfma_f32_16x16x32_bf16(af[i], bfh[j], t, 0, 0, 0);
          if constexpr (SB)
            t = __builtin_amdgcn_mfma_f32_16x16x32_bf16(af[i], bfl[j], t, 0, 0, 0);
          acc[i][j] = t;
        }
    }
  }
  if constexpr (TRANS) __syncthreads();
  #pragma unroll
  for (int i = 0; i < 2; ++i) {
    const int row = m0 + wm + i * 16 + quad * 4;
    #pragma unroll
    for (int j = 0; j < 2; ++j) {
      const int col = n0 + wn + j * 16 + lm;
      const float bv = bias[col];
      #pragma unroll
      for (int r = 0; r < 4; ++r) {
        float x = acc[i][j][r] + bv;
        if (GELU) x = 0.5f * x * (1.0f + erff(x * 0.70710678118654752f));
        const size_t ri = (size_t)(row + r) * CC + col;
        if (RESID == 1) x += residf[ri];
        if (RESID == 2) x += b2f(residh[ri]) + b2f(residl[ri]);
        if constexpr (TRANS) {
          ttile[wm + i * 16 + quad * 4 + r][wn + j * 16 + lm] = x;
        } else {
          const size_t oi = (size_t)(row + r) * ldc + col;
          if (OUTMODE == 0) outf[oi] = x;
          else outh[oi] = f2bf(x);
        }
      }
    }
  }
  if constexpr (TRANS) {
    __syncthreads();
    const int bi = m0 >> 10, s0 = m0 & 1023;
    const int s = tid & 63;
    #pragma unroll
    for (int c0 = 0; c0 < 64; c0 += 4) {
      const int col = c0 + (tid >> 6);
      outf[(size_t)(bi * 512 + n0 + col) * 1024 + s0 + s] = ttile[s][col];
    }
  }
}

// ---------- flash attention: swapped QK^T, reg-staged K/V (T14), setprio -----
// S^T = mfma(K, Q): lane (quad,lm) holds q=lm, k = j*16+quad*4+r  (16 k per lane)
__global__ __launch_bounds__(256) void attn_mfma(
    const unsigned short* __restrict__ QKh, const unsigned short* __restrict__ QKl,
    const unsigned short* __restrict__ Vt, unsigned short* __restrict__ Oh) {
  __shared__ __align__(16) unsigned short Ksh[64 * 64], Ksl[64 * 64];
  __shared__ __align__(16) unsigned short Vts[64 * 64];
  __shared__ __align__(16) unsigned short Pts[4][16 * 64];
  const int f = blockIdx.x, xcd = f & 7, gidx = f >> 3;
  const int bh = (xcd << 3) | (gidx >> 4);
  const int q0 = (gidx & 15) * 64, h = bh & 7, b = bh >> 3;
  const int tid = threadIdx.x, w = tid >> 6, l = tid & 63, quad = l >> 4, lm = l & 15;
  const int LDQ = 2 * CC;
  const size_t qkbase = (size_t)b * SS * LDQ;
  const int srow8 = tid >> 3;
  const int sch8  = ((tid & 7) ^ (srow8 & 7)) * 8;
  const unsigned short* Vg  = Vt + ((size_t)(b * 8 + h) * 64 + srow8) * 1024 + sch8;
  const unsigned short* kgh = QKh + qkbase + (size_t)srow8 * LDQ + CC + h * 64 + sch8;
  const unsigned short* kgl = QKl + qkbase + (size_t)srow8 * LDQ + CC + h * 64 + sch8;
  const int lofs = w * 512 + l * 8;   // per-lane LDS slot (shorts), 16B stride
  short8 qh[2], ql[2];
  {
    const size_t qo = qkbase + (size_t)(q0 + w * 16 + lm) * LDQ + h * 64 + quad * 8;
    qh[0] = *(const short8*)(QKh + qo);
    qh[1] = *(const short8*)(QKh + qo + 32);
    ql[0] = *(const short8*)(QKl + qo);
    ql[1] = *(const short8*)(QKl + qo + 32);
  }
  const f32x4 fzero = {0.f, 0.f, 0.f, 0.f};
  float m = -1e30f, lsum = 0.f;
  f32x4 oacc[4];
  #pragma unroll
  for (int j = 0; j < 4; ++j) oacc[j] = fzero;
  unsigned char* Pb = (unsigned char*)(Pts[w]);
  const int pwbase = lm * 128 + ((quad & 1) << 3);
  const int prbase = lm * 128;
  // prologue: prefetch tile 0 into registers
  short8 s0h = *(const short8*)(kgh);
  short8 s1h = *(const short8*)(kgh + (size_t)32 * LDQ);
  short8 s0l = *(const short8*)(kgl);
  short8 s1l = *(const short8*)(kgl + (size_t)32 * LDQ);
  short8 s0v = *(const short8*)(Vg);
  short8 s1v = *(const short8*)(Vg + 32 * 1024);
  for (int kt = 0; kt < SS; kt += 64) {
    __syncthreads();                     // all waves done reading prev tile
    *(short8*)(Ksh + lofs)        = s0h; // vmcnt drain lands here (covered)
    *(short8*)(Ksh + 2048 + lofs) = s1h;
    *(short8*)(Ksl + lofs)        = s0l;
    *(short8*)(Ksl + 2048 + lofs) = s1l;
    *(short8*)(Vts + lofs)        = s0v;
    *(short8*)(Vts + 2048 + lofs) = s1v;
    __syncthreads();                     // writes visible
    {                                    // issue next tile's loads (hidden)
      const int ktn = (kt + 64) & (SS - 1);
      s0h = *(const short8*)(kgh + (size_t)ktn * LDQ);
      s1h = *(const short8*)(kgh + (size_t)(ktn + 32) * LDQ);
      s0l = *(const short8*)(kgl + (size_t)ktn * LDQ);
      s1l = *(const short8*)(kgl + (size_t)(ktn + 32) * LDQ);
      s0v = *(const short8*)(Vg + ktn);
      s1v = *(const short8*)(Vg + ktn + 32 * 1024);
    }
    f32x4 sc[4];
    __builtin_amdgcn_s_setprio(1);
    {  // st = 0 : A = K fragment, B = Q fragment  ->  S^T
      const int kc = (quad ^ (lm & 7)) * 8;
      #pragma unroll
      for (int j = 0; j < 4; ++j) {
        short8 kh = *(const short8*)(Ksh + (j * 16 + lm) * 64 + kc);
        short8 kl = *(const short8*)(Ksl + (j * 16 + lm) * 64 + kc);
        f32x4 t = __builtin_amdgcn_mfma_f32_16x16x32_bf16(kh, qh[0], fzero, 0, 0, 0);
        t = __builtin_amdgcn_mfma_f32_16x16x32_bf16(kl, qh[0], t, 0, 0, 0);
        t = __builtin_amdgcn_mfma_f32_16x16x32_bf16(kh, ql[0], t, 0, 0, 0);
        sc[j] = t;
      }
    }
    {  // st = 1
      const int kc = ((4 + quad) ^ (lm & 7)) * 8;
      #pragma unroll
      for (int j = 0; j < 4; ++j) {
        short8 kh = *(const short8*)(Ksh + (j * 16 + lm) * 64 + kc);
        short8 kl = *(const short8*)(Ksl + (j * 16 + lm) * 64 + kc);
        f32x4 t = sc[j];
        t = __builtin_amdgcn_mfma_f32_16x16x32_bf16(kh, qh[1], t, 0, 0, 0);
        t = __builtin_amdgcn_mfma_f32_16x16x32_bf16(kl, qh[1], t, 0, 0, 0);
        t = __builtin_amdgcn_mfma_f32_16x16x32_bf16(kh, ql[1], t, 0, 0, 0);
        sc[j] = t;
      }
    }
    __builtin_amdgcn_s_setprio(0);
    // lane-local max over 16 k + cross-quad butterfly (2 shfl)
    float mt0 = fmaxf(fmaxf(sc[0][0], sc[0][1]), fmaxf(sc[0][2], sc[0][3]));
    float mt1 = fmaxf(fmaxf(sc[1][0], sc[1][1]), fmaxf(sc[1][2], sc[1][3]));
    float mt2 = fmaxf(fmaxf(sc[2][0], sc[2][1]), fmaxf(sc[2][2], sc[2][3]));
    float mt3 = fmaxf(fmaxf(sc[3][0], sc[3][1]), fmaxf(sc[3][2], sc[3][3]));
    float mt = fmaxf(fmaxf(mt0, mt1), fmaxf(mt2, mt3));
    mt = fmaxf(mt, __shfl_xor(mt, 16, 64));
    mt = fmaxf(mt, __shfl_xor(mt, 32, 64));
    const float mnew = fmaxf(m, mt);
    if (__any(mnew > m)) {
      const float alpha = exp2f(m - mnew);
      m = mnew;
      lsum *= alpha;
      #pragma unroll
      for (int j = 0; j < 4; ++j)
        #pragma unroll
        for (int r = 0; r < 4; ++r) oacc[j][r] *= alpha;
    }
    float ls = 0.f;
    #pragma unroll
    for (int j = 0; j < 4; ++j)
      #pragma unroll
      for (int r = 0; r < 4; ++r) {
        sc[j][r] = exp2f(sc[j][r] - m);
        ls += sc[j][r];
      }
    ls += __shfl_xor(ls, 16, 64);
    ls += __shfl_xor(ls, 32, 64);
    lsum += ls;
    // pack P^T: per j, 4 k-contiguous bf16 (truncated) -> one b64 LDS write
    #pragma unroll
    for (int j = 0; j < 4; ++j) {
      union { float f; unsigned int u; } c0, c1, c2, c3;
      c0.f = sc[j][0]; c1.f = sc[j][1]; c2.f = sc[j][2]; c3.f = sc[j][3];
      u32x2 pk;
      pk[0] = __builtin_amdgcn_perm(c1.u, c0.u, 0x07060302u);  // [bf(s0)|bf(s1)]
      pk[1] = __builtin_amdgcn_perm(c3.u, c2.u, 0x07060302u);  // [bf(s2)|bf(s3)]
      const int slot = ((j << 1) | (quad >> 1)) ^ (lm & 7);
      *(u32x2*)(Pb + pwbase + (slot << 4)) = pk;
    }
    // PV: O^T += V^T-frag x P^T-frag
    __builtin_amdgcn_s_setprio(1);
    #pragma unroll
    for (int st = 0; st < 2; ++st) {
      short8 pf = *(const short8*)(Pb + prbase + ((((st << 2) | quad) ^ (lm & 7)) << 4));
      const int kc = ((st * 4 + quad) ^ (lm & 7)) * 8;
      #pragma unroll
      for (int j = 0; j < 4; ++j) {
        short8 vv = *(const short8*)(Vts + (j * 16 + lm) * 64 + kc);
        oacc[j] = __builtin_amdgcn_mfma_f32_16x16x32_bf16(vv, pf, oacc[j], 0, 0, 0);
      }
    }
    __builtin_amdgcn_s_setprio(0);
  }
  const float inv = 1.f / lsum;
  // lane holds O[q=lm][d = j*16 + quad*4 + r] -> 4x 8B stores
  const size_t obase =
      (size_t)b * SS * CC + (size_t)(q0 + w * 16 + lm) * CC + h * 64 + quad * 4;
  #pragma unroll
  for (int j = 0; j < 4; ++j) {
    ushort4v pk;
    #pragma unroll
    for (int r = 0; r < 4; ++r) pk[r] = f2bf(oacc[j][r] * inv);
    *(ushort4v*)(Oh + obase + j * 16) = pk;
  }
}

extern "C" void kernel_launch(void* const* d_in, const int* in_sizes, int n_in,
                              void* d_out, int out_size, void* d_ws, size_t ws_size,
                              hipStream_t stream) {
  const float* x    = (const float*)d_in[0];
  const float* K_W  = (const float*)d_in[2];
  const float* K_b  = (const float*)d_in[3];
  const float* Q_W  = (const float*)d_in[4];
  const float* Q_b  = (const float*)d_in[5];
  const float* V_W  = (const float*)d_in[6];
  const float* V_b  = (const float*)d_in[7];
  const float* O_W  = (const float*)d_in[8];
  const float* O_b  = (const float*)d_in[9];
  const float* ln1g = (const float*)d_in[10];
  const float* ln1b = (const float*)d_in[11];
  const float* ln2g = (const float*)d_in[12];
  const float* ln2b = (const float*)d_in[13];
  const float* W1   = (const float*)d_in[14];
  const float* b1   = (const float*)d_in[15];
  const float* W2   = (const float*)d_in[16];
  const float* b2   = (const float*)d_in[17];
  float* out = (float*)d_out;

  unsigned char* ws = (unsigned char*)d_ws;
  const size_t MB = 1u << 20;
  unsigned short* qkh   = (unsigned short*)(ws);             // (B,S,1024) 16MB
  unsigned short* qkl   = (unsigned short*)(ws + 16 * MB);   // 16MB
  unsigned short* vt    = (unsigned short*)(ws + 32 * MB);   // (B,NH,HD,S) 8MB
  unsigned short* ln1h  = (unsigned short*)(ws + 40 * MB);   // 8MB
  unsigned short* ln1l  = (unsigned short*)(ws + 48 * MB);   // 8MB
  float* xsf            = (float*)(ws + 56 * MB);            // (B,S,C) f32 16MB
  unsigned short* oh    = ln1h;
  float* out1           = (float*)(ws + 72 * MB);            // 16MB
  unsigned short* ln2h  = qkh;
  unsigned short* geluh = (unsigned short*)(ws + 8 * MB);
  unsigned short* BtAll = (unsigned short*)(ws + 88 * MB);
  unsigned short* BtQKh = BtAll;
  unsigned short* BtVh  = BtAll + 1024 * 512;
  unsigned short* BtQKl = BtVh + 512 * 512;
  unsigned short* BtOh  = BtQKl + 1024 * 512;
  unsigned short* BtOl  = BtOh + 512 * 512;
  unsigned short* BtW1h = BtOl + 512 * 512;
  unsigned short* BtW2h = BtW1h + 512 * 512;
  float* qkvb           = (float*)(BtW2h + 512 * 512);
  float2* mustd         = (float2*)(ws + 96 * MB);

  dim3 tb32(32, 8);
  convert_and_stats<<<1536 + 128, 256, 0, stream>>>(
      Q_W, K_W, V_W, O_W, W1, W2, Q_b, K_b, V_b,
      BtQKh, BtQKl, BtVh, BtOh, BtOl, BtW1h, BtW2h, qkvb, x, mustd);
  ln1_apply<<<dim3(SS / 32, CC / 32, BB), tb32, 0, stream>>>(
      x, mustd, ln1g, ln1b, ln1h, ln1l, xsf);
  gemm_qkv<<<768, 256, 0, stream>>>(
      ln1h, ln1l, BtAll, BtQKl, qkvb, qkh, qkl, vt);
  attn_mfma<<<1024, 256, 0, stream>>>(qkh, qkl, vt, oh);
  gemm64<1, 0, 0, 1, 0><<<1024, 256, 0, stream>>>(
      oh, BtOh, BtOl, O_b, xsf, nullptr, nullptr, nullptr, out1, CC);
  ln_bf16_k<<<BB * SS / 4, 256, 0, stream>>>(out1, ln2g, ln2b, ln2h);
  gemm64<0, 1, 1, 0, 0><<<1024, 256, 0, stream>>>(
      ln2h, BtW1h, nullptr, b1, nullptr, nullptr, nullptr, geluh, nullptr, CC);
  gemm64<0, 0, 0, 1, 1><<<1024, 256, 0, stream>>>(
      geluh, BtW2h, nullptr, b2, out1, nullptr, nullptr, nullptr, out, CC);
}

// Round 11
// 257.474 us; speedup vs baseline: 1.1288x; 1.0368x over previous
//
#include <hip/hip_runtime.h>
#include <math.h>

#define BB 8
#define CC 512
#define SS 1024
#define NHH 8
#define HDD 64
#define KD 512

typedef __attribute__((ext_vector_type(8))) short short8;
typedef __attribute__((ext_vector_type(4))) float f32x4;
typedef __attribute__((ext_vector_type(4))) unsigned short ushort4v;
typedef __attribute__((ext_vector_type(8))) unsigned short ushort8v;
typedef __attribute__((ext_vector_type(2))) unsigned int u32x2;

__device__ __forceinline__ unsigned short f2bf(float x) {
  union { float f; unsigned int u; } c; c.f = x;
  unsigned int r = (c.u + 0x7FFFu + ((c.u >> 16) & 1u)) >> 16;
  return (unsigned short)r;
}
__device__ __forceinline__ float b2f(unsigned short h) {
  union { unsigned int u; float f; } c; c.u = ((unsigned int)h) << 16; return c.f;
}

#define GLD_LDS(gp, lp) __builtin_amdgcn_global_load_lds( \
    (const __attribute__((address_space(1))) void*)(gp),  \
    (__attribute__((address_space(3))) void*)(lp), 16, 0, 0)

// ---------- block-wide sum over 256 threads (4 waves) ----------
__device__ __forceinline__ float block_reduce_sum(float v) {
  __shared__ float sm[4];
  #pragma unroll
  for (int o = 32; o > 0; o >>= 1) v += __shfl_down(v, o, 64);
  if ((threadIdx.x & 63) == 0) sm[threadIdx.x >> 6] = v;
  __syncthreads();
  float r = (sm[0] + sm[1]) + (sm[2] + sm[3]);
  __syncthreads();
  return r;
}

// ---------- LN1 apply + transpose: -> ln1 h/l + xs f32 (B,S,C) ---------------
__global__ __launch_bounds__(256) void ln1_apply(
    const float* __restrict__ x, const float2* __restrict__ mustd,
    const float* __restrict__ g, const float* __restrict__ be,
    unsigned short* __restrict__ yh, unsigned short* __restrict__ yl,
    float* __restrict__ xf) {
  __shared__ float tile[32][33];
  const int b = blockIdx.z, c0 = blockIdx.y * 32, s0 = blockIdx.x * 32;
  const int tx = threadIdx.x, ty = threadIdx.y;
  const float* xb = x + ((size_t)b * CC + c0) * SS + s0;
  #pragma unroll
  for (int i = ty; i < 32; i += 8)
    tile[i][tx] = xb[(size_t)i * SS + tx];
  __syncthreads();
  const float gc = g[c0 + tx], bc = be[c0 + tx];
  #pragma unroll
  for (int i = ty; i < 32; i += 8) {
    const float2 ms = mustd[b * SS + s0 + i];
    const float v = tile[tx][i];
    const float y = (v - ms.x) * ms.y * gc + bc;
    const size_t oi = ((size_t)b * SS + s0 + i) * CC + c0 + tx;
    const unsigned short hy = f2bf(y);
    yh[oi] = hy; yl[oi] = f2bf(y - b2f(hy));
    xf[oi] = v;
  }
}

// ---------- LayerNorm (C=512), one wave per row: no barriers, no LDS ---------
__global__ __launch_bounds__(256) void ln_bf16_k(const float* __restrict__ in,
                                                 const float* __restrict__ g,
                                                 const float* __restrict__ be,
                                                 unsigned short* __restrict__ outh) {
  const int wv = threadIdx.x >> 6, ln = threadIdx.x & 63;
  const size_t row = (size_t)blockIdx.x * 4 + wv;
  const float* r = in + row * CC + ln * 8;
  const float4 v0 = *(const float4*)(r);
  const float4 v1 = *(const float4*)(r + 4);
  float s = (v0.x + v0.y + v0.z + v0.w) + (v1.x + v1.y + v1.z + v1.w);
  #pragma unroll
  for (int o = 32; o > 0; o >>= 1) s += __shfl_xor(s, o, 64);
  const float mu = s * (1.0f / CC);
  float d[8] = {v0.x - mu, v0.y - mu, v0.z - mu, v0.w - mu,
                v1.x - mu, v1.y - mu, v1.z - mu, v1.w - mu};
  float q = 0.f;
  #pragma unroll
  for (int i = 0; i < 8; ++i) q += d[i] * d[i];
  #pragma unroll
  for (int o = 32; o > 0; o >>= 1) q += __shfl_xor(q, o, 64);
  const float rstd = rsqrtf(q * (1.0f / CC) + 1e-5f);
  const float4 g0 = *(const float4*)(g + ln * 8);
  const float4 g1 = *(const float4*)(g + ln * 8 + 4);
  const float4 b0 = *(const float4*)(be + ln * 8);
  const float4 b1 = *(const float4*)(be + ln * 8 + 4);
  const float gv[8] = {g0.x, g0.y, g0.z, g0.w, g1.x, g1.y, g1.z, g1.w};
  const float bv[8] = {b0.x, b0.y, b0.z, b0.w, b1.x, b1.y, b1.z, b1.w};
  ushort8v o8;
  #pragma unroll
  for (int i = 0; i < 8; ++i) o8[i] = f2bf(d[i] * rstd * gv[i] + bv[i]);
  *(ushort8v*)(outh + row * CC + ln * 8) = o8;
}

// ---------- weight convert + LN1 stats, one flat launch ----------------------
// blocks [0,1536): weight panels (as before); blocks [1536,1664): ln1 stats.
// Q_W / Q_b pre-scaled by 1/sqrt(512)*log2(e).
__global__ __launch_bounds__(256) void convert_and_stats(
    const float* __restrict__ QW, const float* __restrict__ KW,
    const float* __restrict__ VW, const float* __restrict__ OW,
    const float* __restrict__ W1, const float* __restrict__ W2,
    const float* __restrict__ Qb, const float* __restrict__ Kb,
    const float* __restrict__ Vb,
    unsigned short* __restrict__ BtQKh, unsigned short* __restrict__ BtQKl,
    unsigned short* __restrict__ BtVh,
    unsigned short* __restrict__ BtOh, unsigned short* __restrict__ BtOl,
    unsigned short* __restrict__ BtW1h, unsigned short* __restrict__ BtW2h,
    float* __restrict__ qkvb,
    const float* __restrict__ x, float2* __restrict__ mustd) {
  const int bid = blockIdx.x;
  if (bid < 1536) {
    const float SCL = 0.044194173824159216f * 1.4426950408889634f;
    __shared__ float tile[32][33];
    const int bx = bid & 15, by = (bid >> 4) & 1, p = bid >> 5;
    const int wsel = p >> 3, sub = p & 7;
    const int k0 = bx * 32, d0 = by * 32;
    const int tx = threadIdx.x & 31, ty = threadIdx.x >> 5;
    const float* w; int rs; unsigned short *dh, *dl; int nbase; float mul = 1.0f;
    switch (wsel) {
      case 0:  w = QW + sub * 32768; rs = 64;  dh = BtQKh; dl = BtQKl;  nbase = sub * 64; mul = SCL; break;
      case 1:  w = KW + sub * 32768; rs = 64;  dh = BtQKh; dl = BtQKl;  nbase = 512 + sub * 64;  break;
      case 2:  w = VW + sub * 32768; rs = 64;  dh = BtVh;  dl = nullptr; nbase = sub * 64;       break;
      case 3:  w = OW + sub * 64;    rs = 512; dh = BtOh;  dl = BtOl;   nbase = sub * 64;        break;
      case 4:  w = W1 + sub * 64;    rs = 512; dh = BtW1h; dl = nullptr; nbase = sub * 64;       break;
      default: w = W2 + sub * 64;    rs = 512; dh = BtW2h; dl = nullptr; nbase = sub * 64;       break;
    }
    for (int i = ty; i < 32; i += 8)
      tile[i][tx] = w[(size_t)(k0 + i) * rs + d0 + tx];
    __syncthreads();
    for (int i = ty; i < 32; i += 8) {
      float f = tile[tx][i] * mul;
      unsigned short h = f2bf(f);
      size_t idx = (size_t)(nbase + d0 + i) * KD + k0 + tx;
      dh[idx] = h;
      if (dl) dl[idx] = f2bf(f - b2f(h));
    }
    if (bid == 0) {
      int t = threadIdx.x;
      for (int i = t; i < 1536; i += 256)
        qkvb[i] = i < 512 ? Qb[i] * SCL : (i < 1024 ? Kb[i - 512] : Vb[i - 1024]);
    }
  } else {
    const int bid2 = bid - 1536;
    const int b = bid2 >> 4, s0 = (bid2 & 15) * 64;
    const int sl = threadIdx.x & 63, cg = threadIdx.x >> 6;
    const float* xp = x + (size_t)b * CC * SS + s0 + sl;
    float ps = 0.f, pq = 0.f;
    #pragma unroll 8
    for (int i = 0; i < 128; ++i) {
      const float v = xp[(size_t)(cg * 128 + i) * SS];
      ps += v; pq += v * v;
    }
    __shared__ float sred[2][4][64];
    sred[0][cg][sl] = ps; sred[1][cg][sl] = pq;
    __syncthreads();
    if (cg == 0) {
      const float s = (sred[0][0][sl] + sred[0][1][sl]) + (sred[0][2][sl] + sred[0][3][sl]);
      const float q = (sred[1][0][sl] + sred[1][1][sl]) + (sred[1][2][sl] + sred[1][3][sl]);
      const float mu = s * (1.0f / CC);
      const float rs = rsqrtf(q * (1.0f / CC) - mu * mu + 1e-5f);
      mustd[b * SS + s0 + sl] = make_float2(mu, rs);
    }
  }
}

// ---------- fused QKV projection GEMM, 128x128 tiles, XCD-swizzled grid ------
__global__ __launch_bounds__(256) void gemm_qkv(
    const unsigned short* __restrict__ Ah, const unsigned short* __restrict__ Al,
    const unsigned short* __restrict__ Bth, const unsigned short* __restrict__ Btl,
    const float* __restrict__ bias,
    unsigned short* __restrict__ qkh, unsigned short* __restrict__ qkl,
    unsigned short* __restrict__ vt) {
  __shared__ __align__(16) unsigned short smem[4 * 128 * 32];
  unsigned short* As = smem;
  unsigned short* Bs = smem + 2 * 128 * 32;
  const int tid = threadIdx.x;
  const int w = tid >> 6, l = tid & 63, quad = l >> 4, lm = l & 15;
  const int f = blockIdx.x, xcd = f & 7, gidx = f >> 3;
  const int n0 = (gidx >> 3) * 128;
  const int m0 = (((gidx & 7) << 3) | xcd) * 128;
  const bool splitB = n0 < 1024;
  const int wm = (w >> 1) * 64, wn = (w & 1) * 64;
  const int srow = tid >> 2;
  const int sch = (((tid & 3) ^ (srow & 3)) * 8);
  const unsigned short* Agh = Ah + (size_t)(m0 + srow) * KD + sch;
  const unsigned short* Agl = Al + (size_t)(m0 + srow) * KD + sch;
  const unsigned short* Bgh = Bth + (size_t)(n0 + srow) * KD + sch;
  const unsigned short* Bgl = Btl + (size_t)(n0 + srow) * KD + sch;
  unsigned short* Aswh = As + w * 512;
  unsigned short* Aswl = As + 4096 + w * 512;
  unsigned short* Bswh = Bs + w * 512;
  unsigned short* Bswl = Bs + 4096 + w * 512;
  const int rch = ((quad ^ (lm & 3)) * 8);
  const f32x4 fzero = {0.f, 0.f, 0.f, 0.f};
  f32x4 acc[4][4];
  #pragma unroll
  for (int i = 0; i < 4; ++i)
    #pragma unroll
    for (int j = 0; j < 4; ++j) acc[i][j] = fzero;
  for (int k0 = 0; k0 < KD; k0 += 32) {
    __syncthreads();
    GLD_LDS(Agh + k0, Aswh);
    GLD_LDS(Agh + k0 + 64 * KD, Aswh + 2048);
    GLD_LDS(Agl + k0, Aswl);
    GLD_LDS(Agl + k0 + 64 * KD, Aswl + 2048);
    GLD_LDS(Bgh + k0, Bswh);
    GLD_LDS(Bgh + k0 + 64 * KD, Bswh + 2048);
    if (splitB) {
      GLD_LDS(Bgl + k0, Bswl);
      GLD_LDS(Bgl + k0 + 64 * KD, Bswl + 2048);
    }
    __syncthreads();
    short8 afh[4], afl[4], bfh[4], bfl[4];
    #pragma unroll
    for (int i = 0; i < 4; ++i) {
      afh[i] = *(const short8*)(As + (wm + i * 16 + lm) * 32 + rch);
      afl[i] = *(const short8*)(As + 4096 + (wm + i * 16 + lm) * 32 + rch);
    }
    #pragma unroll
    for (int j = 0; j < 4; ++j)
      bfh[j] = *(const short8*)(Bs + (wn + j * 16 + lm) * 32 + rch);
    if (splitB) {
      #pragma unroll
      for (int j = 0; j < 4; ++j)
        bfl[j] = *(const short8*)(Bs + 4096 + (wn + j * 16 + lm) * 32 + rch);
      #pragma unroll
      for (int i = 0; i < 4; ++i)
        #pragma unroll
        for (int j = 0; j < 4; ++j) {
          f32x4 t = acc[i][j];
          t = __builtin_amdgcn_mfma_f32_16x16x32_bf16(afh[i], bfh[j], t, 0, 0, 0);
          t = __builtin_amdgcn_mfma_f32_16x16x32_bf16(afh[i], bfl[j], t, 0, 0, 0);
          t = __builtin_amdgcn_mfma_f32_16x16x32_bf16(afl[i], bfh[j], t, 0, 0, 0);
          acc[i][j] = t;
        }
    } else {
      #pragma unroll
      for (int i = 0; i < 4; ++i)
        #pragma unroll
        for (int j = 0; j < 4; ++j)
          acc[i][j] = __builtin_amdgcn_mfma_f32_16x16x32_bf16(afh[i], bfh[j], acc[i][j], 0, 0, 0);
    }
  }
  if (splitB) {
    #pragma unroll
    for (int i = 0; i < 4; ++i) {
      const int row = m0 + wm + i * 16 + quad * 4;
      #pragma unroll
      for (int j = 0; j < 4; ++j) {
        const int ncol = n0 + wn + j * 16 + lm;
        const float bv = bias[ncol];
        #pragma unroll
        for (int r = 0; r < 4; ++r) {
          const float xv = acc[i][j][r] + bv;
          const size_t oi = (size_t)(row + r) * 1024 + ncol;
          unsigned short h = f2bf(xv);
          qkh[oi] = h;
          qkl[oi] = f2bf(xv - b2f(h));
        }
      }
    }
  } else {
    __syncthreads();
    #pragma unroll
    for (int i = 0; i < 4; ++i) {
      const int mlb = wm + i * 16 + quad * 4;
      #pragma unroll
      for (int j = 0; j < 4; ++j) {
        const int nl = wn + j * 16 + lm;
        const float bv = bias[n0 + nl];
        ushort4v pk;
        #pragma unroll
        for (int r = 0; r < 4; ++r) pk[r] = f2bf(acc[i][j][r] + bv);
        const int chunk = ((mlb >> 3) ^ (nl & 15));
        *(ushort4v*)(smem + nl * 128 + chunk * 8 + (mlb & 7)) = pk;
      }
    }
    __syncthreads();
    const int tn = tid >> 4, tc = tid & 15;
    const int bb2 = m0 >> 10, sbase = m0 & 1023;
    #pragma unroll
    for (int pass = 0; pass < 8; ++pass) {
      const int nl = pass * 16 + tn;
      const int hh = (n0 - 1024 + nl) >> 6, dd = nl & 63;
      short8 v8 = *(const short8*)(smem + nl * 128 + ((tc ^ (nl & 15)) * 8));
      *(short8*)(vt + ((size_t)(bb2 * 8 + hh) * 64 + dd) * 1024 + sbase + tc * 8) = v8;
    }
  }
}

// ---------- 64x64-tile GEMM, BK=64, GLD staging, XCD-swizzled grid -----------
template<int SB, int GELU, int OUTMODE, int RESID, int TRANS>
__global__ __launch_bounds__(256) void gemm64(
    const unsigned short* __restrict__ Ah,
    const unsigned short* __restrict__ Bh, const unsigned short* __restrict__ Bl,
    const float* __restrict__ bias, const float* __restrict__ residf,
    const unsigned short* __restrict__ residh, const unsigned short* __restrict__ residl,
    unsigned short* __restrict__ outh, float* __restrict__ outf, int ldc) {
  constexpr int STAGE = (SB ? 3 : 2) * 8192;
  constexpr int TSIZE = TRANS ? 64 * 65 * 4 : 0;
  __shared__ __align__(16) unsigned char smem[STAGE > TSIZE ? STAGE : TSIZE];
  unsigned short* As  = (unsigned short*)smem;
  unsigned short* Bs  = (unsigned short*)(smem + 8192);
  unsigned short* Bls = (unsigned short*)(smem + 16384);
  float (*ttile)[65]  = (float(*)[65])smem;
  const int tid = threadIdx.x;
  const int w = tid >> 6, l = tid & 63, quad = l >> 4, lm = l & 15;
  const int f = blockIdx.x, xcd = f & 7, gidx = f >> 3;
  const int n0 = (gidx >> 4) * 64;
  const int m0 = (((gidx & 15) << 3) | xcd) * 64;
  const int wm = (w >> 1) * 32, wn = (w & 1) * 32;
  const int srow8 = tid >> 3;
  const int sch8  = ((tid & 7) ^ (srow8 & 7)) * 8;
  const unsigned short* Ag  = Ah + (size_t)(m0 + srow8) * KD + sch8;
  const unsigned short* Bg  = Bh + (size_t)(n0 + srow8) * KD + sch8;
  const unsigned short* Bgl = SB ? Bl + (size_t)(n0 + srow8) * KD + sch8 : nullptr;
  const f32x4 fzero = {0.f, 0.f, 0.f, 0.f};
  f32x4 acc[2][2];
  #pragma unroll
  for (int i = 0; i < 2; ++i)
    #pragma unroll
    for (int j = 0; j < 2; ++j) acc[i][j] = fzero;
  for (int k0 = 0; k0 < KD; k0 += 64) {
    __syncthreads();
    GLD_LDS(Ag + k0, As + w * 512);
    GLD_LDS(Ag + k0 + 32 * KD, As + 2048 + w * 512);
    GLD_LDS(Bg + k0, Bs + w * 512);
    GLD_LDS(Bg + k0 + 32 * KD, Bs + 2048 + w * 512);
    if constexpr (SB) {
      GLD_LDS(Bgl + k0, Bls + w * 512);
      GLD_LDS(Bgl + k0 + 32 * KD, Bls + 2048 + w * 512);
    }
    __syncthreads();
    #pragma unroll
    for (int ks = 0; ks < 2; ++ks) {
      const int kc = ((ks * 4 + quad) ^ (lm & 7)) * 8;
      short8 af[2], bfh[2], bfl[2];
      #pragma unroll
      for (int i = 0; i < 2; ++i)
        af[i] = *(const short8*)(As + (wm + i * 16 + lm) * 64 + kc);
      #pragma unroll
      for (int j = 0; j < 2; ++j)
        bfh[j] = *(const short8*)(Bs + (wn + j * 16 + lm) * 64 + kc);
      if constexpr (SB) {
        #pragma unroll
        for (int j = 0; j < 2; ++j)
          bfl[j] = *(const short8*)(Bls + (wn + j * 16 + lm) * 64 + kc);
      }
      #pragma unroll
      for (int i = 0; i < 2; ++i)
        #pragma unroll
        for (int j = 0; j < 2; ++j) {
          f32x4 t = acc[i][j];
          t = __builtin_amdgcn_mfma_f32_16x16x32_bf16(af[i], bfh[j], t, 0, 0, 0);
          if constexpr (SB)
            t = __builtin_amdgcn_mfma_f32_16x16x32_bf16(af[i], bfl[j], t, 0, 0, 0);
          acc[i][j] = t;
        }
    }
  }
  if constexpr (TRANS) __syncthreads();
  #pragma unroll
  for (int i = 0; i < 2; ++i) {
    const int row = m0 + wm + i * 16 + quad * 4;
    #pragma unroll
    for (int j = 0; j < 2; ++j) {
      const int col = n0 + wn + j * 16 + lm;
      const float bv = bias[col];
      #pragma unroll
      for (int r = 0; r < 4; ++r) {
        float x = acc[i][j][r] + bv;
        if (GELU) x = 0.5f * x * (1.0f + erff(x * 0.70710678118654752f));
        const size_t ri = (size_t)(row + r) * CC + col;
        if (RESID == 1) x += residf[ri];
        if (RESID == 2) x += b2f(residh[ri]) + b2f(residl[ri]);
        if constexpr (TRANS) {
          ttile[wm + i * 16 + quad * 4 + r][wn + j * 16 + lm] = x;
        } else {
          const size_t oi = (size_t)(row + r) * ldc + col;
          if (OUTMODE == 0) outf[oi] = x;
          else outh[oi] = f2bf(x);
        }
      }
    }
  }
  if constexpr (TRANS) {
    __syncthreads();
    const int bi = m0 >> 10, s0 = m0 & 1023;
    const int s = tid & 63;
    #pragma unroll
    for (int c0 = 0; c0 < 64; c0 += 4) {
      const int col = c0 + (tid >> 6);
      outf[(size_t)(bi * 512 + n0 + col) * 1024 + s0 + s] = ttile[s][col];
    }
  }
}

// ---------- flash attention: swapped QK^T, 32 q-rows per wave ----------------
// Each wave owns 2 q-fragments (32 rows); K/V fragments are read from LDS ONCE
// into registers and consumed by both q-fragments -> per-CU LDS-pipe traffic
// drops ~0.6x (it was the dominant pipe: 28 b128-reads/tile/wave).
// grid 512 (= B*H*(S/128)), 2 blocks/CU, 8 waves/CU.
__global__ __launch_bounds__(256) void attn_mfma(
    const unsigned short* __restrict__ QKh, const unsigned short* __restrict__ QKl,
    const unsigned short* __restrict__ Vt, unsigned short* __restrict__ Oh) {
  __shared__ __align__(16) unsigned short Ksh[64 * 64], Ksl[64 * 64];
  __shared__ __align__(16) unsigned short Vts[64 * 64];
  __shared__ __align__(16) unsigned short Pts[4][2][16 * 64];
  const int f = blockIdx.x, xcd = f & 7, gidx = f >> 3;
  const int bh = (xcd << 3) | (gidx >> 3);
  const int q0 = (gidx & 7) * 128, h = bh & 7, b = bh >> 3;
  const int tid = threadIdx.x, w = tid >> 6, l = tid & 63, quad = l >> 4, lm = l & 15;
  const int LDQ = 2 * CC;
  const size_t qkbase = (size_t)b * SS * LDQ;
  const int srow8 = tid >> 3;
  const int sch8  = ((tid & 7) ^ (srow8 & 7)) * 8;
  const unsigned short* Vg  = Vt + ((size_t)(b * 8 + h) * 64 + srow8) * 1024 + sch8;
  const unsigned short* kgh = QKh + qkbase + (size_t)srow8 * LDQ + CC + h * 64 + sch8;
  const unsigned short* kgl = QKl + qkbase + (size_t)srow8 * LDQ + CC + h * 64 + sch8;
  const int lofs = w * 512 + l * 8;   // per-lane LDS slot (shorts), 16B stride
  short8 qh[2][2], ql[2][2];
  #pragma unroll
  for (int qi = 0; qi < 2; ++qi) {
    const size_t qo =
        qkbase + (size_t)(q0 + w * 32 + qi * 16 + lm) * LDQ + h * 64 + quad * 8;
    qh[qi][0] = *(const short8*)(QKh + qo);
    qh[qi][1] = *(const short8*)(QKh + qo + 32);
    ql[qi][0] = *(const short8*)(QKl + qo);
    ql[qi][1] = *(const short8*)(QKl + qo + 32);
  }
  const f32x4 fzero = {0.f, 0.f, 0.f, 0.f};
  float m[2] = {-1e30f, -1e30f}, lsum[2] = {0.f, 0.f};
  f32x4 oacc[2][4];
  #pragma unroll
  for (int qi = 0; qi < 2; ++qi)
    #pragma unroll
    for (int j = 0; j < 4; ++j) oacc[qi][j] = fzero;
  const int pwbase = lm * 128 + ((quad & 1) << 3);
  const int prbase = lm * 128;
  // prologue: prefetch tile 0 into registers
  short8 s0h = *(const short8*)(kgh);
  short8 s1h = *(const short8*)(kgh + (size_t)32 * LDQ);
  short8 s0l = *(const short8*)(kgl);
  short8 s1l = *(const short8*)(kgl + (size_t)32 * LDQ);
  short8 s0v = *(const short8*)(Vg);
  short8 s1v = *(const short8*)(Vg + 32 * 1024);
  for (int kt = 0; kt < SS; kt += 64) {
    __syncthreads();                     // all waves done reading prev tile
    *(short8*)(Ksh + lofs)        = s0h; // vmcnt drain lands here (covered)
    *(short8*)(Ksh + 2048 + lofs) = s1h;
    *(short8*)(Ksl + lofs)        = s0l;
    *(short8*)(Ksl + 2048 + lofs) = s1l;
    *(short8*)(Vts + lofs)        = s0v;
    *(short8*)(Vts + 2048 + lofs) = s1v;
    __syncthreads();                     // writes visible
    {                                    // issue next tile's loads (hidden)
      const int ktn = (kt + 64) & (SS - 1);
      s0h = *(const short8*)(kgh + (size_t)ktn * LDQ);
      s1h = *(const short8*)(kgh + (size_t)(ktn + 32) * LDQ);
      s0l = *(const short8*)(kgl + (size_t)ktn * LDQ);
      s1l = *(const short8*)(kgl + (size_t)(ktn + 32) * LDQ);
      s0v = *(const short8*)(Vg + ktn);
      s1v = *(const short8*)(Vg + ktn + 32 * 1024);
    }
    f32x4 sc[2][4];
    __builtin_amdgcn_s_setprio(1);
    {  // st = 0 : K fragments read once, consumed by both q-fragments
      const int kc = (quad ^ (lm & 7)) * 8;
      short8 kh[4], kl[4];
      #pragma unroll
      for (int j = 0; j < 4; ++j) {
        kh[j] = *(const short8*)(Ksh + (j * 16 + lm) * 64 + kc);
        kl[j] = *(const short8*)(Ksl + (j * 16 + lm) * 64 + kc);
      }
      #pragma unroll
      for (int qi = 0; qi < 2; ++qi)
        #pragma unroll
        for (int j = 0; j < 4; ++j) {
          f32x4 t = __builtin_amdgcn_mfma_f32_16x16x32_bf16(kh[j], qh[qi][0], fzero, 0, 0, 0);
          t = __builtin_amdgcn_mfma_f32_16x16x32_bf16(kl[j], qh[qi][0], t, 0, 0, 0);
          t = __builtin_amdgcn_mfma_f32_16x16x32_bf16(kh[j], ql[qi][0], t, 0, 0, 0);
          sc[qi][j] = t;
        }
    }
    {  // st = 1
      const int kc = ((4 + quad) ^ (lm & 7)) * 8;
      short8 kh[4], kl[4];
      #pragma unroll
      for (int j = 0; j < 4; ++j) {
        kh[j] = *(const short8*)(Ksh + (j * 16 + lm) * 64 + kc);
        kl[j] = *(const short8*)(Ksl + (j * 16 + lm) * 64 + kc);
      }
      #pragma unroll
      for (int qi = 0; qi < 2; ++qi)
        #pragma unroll
        for (int j = 0; j < 4; ++j) {
          f32x4 t = sc[qi][j];
          t = __builtin_amdgcn_mfma_f32_16x16x32_bf16(kh[j], qh[qi][1], t, 0, 0, 0);
          t = __builtin_amdgcn_mfma_f32_16x16x32_bf16(kl[j], qh[qi][1], t, 0, 0, 0);
          t = __builtin_amdgcn_mfma_f32_16x16x32_bf16(kh[j], ql[qi][1], t, 0, 0, 0);
          sc[qi][j] = t;
        }
    }
    __builtin_amdgcn_s_setprio(0);
    // per-q-fragment softmax: lane-local max + 2-step cross-quad butterfly
    #pragma unroll
    for (int qi = 0; qi < 2; ++qi) {
      float mt0 = fmaxf(fmaxf(sc[qi][0][0], sc[qi][0][1]), fmaxf(sc[qi][0][2], sc[qi][0][3]));
      float mt1 = fmaxf(fmaxf(sc[qi][1][0], sc[qi][1][1]), fmaxf(sc[qi][1][2], sc[qi][1][3]));
      float mt2 = fmaxf(fmaxf(sc[qi][2][0], sc[qi][2][1]), fmaxf(sc[qi][2][2], sc[qi][2][3]));
      float mt3 = fmaxf(fmaxf(sc[qi][3][0], sc[qi][3][1]), fmaxf(sc[qi][3][2], sc[qi][3][3]));
      float mt = fmaxf(fmaxf(mt0, mt1), fmaxf(mt2, mt3));
      mt = fmaxf(mt, __shfl_xor(mt, 16, 64));
      mt = fmaxf(mt, __shfl_xor(mt, 32, 64));
      const float mnew = fmaxf(m[qi], mt);
      if (__any(mnew > m[qi])) {
        const float alpha = exp2f(m[qi] - mnew);
        m[qi] = mnew;
        lsum[qi] *= alpha;
        #pragma unroll
        for (int j = 0; j < 4; ++j)
          #pragma unroll
          for (int r = 0; r < 4; ++r) oacc[qi][j][r] *= alpha;
      }
      float ls = 0.f;
      #pragma unroll
      for (int j = 0; j < 4; ++j)
        #pragma unroll
        for (int r = 0; r < 4; ++r) {
          sc[qi][j][r] = exp2f(sc[qi][j][r] - m[qi]);
          ls += sc[qi][j][r];
        }
      ls += __shfl_xor(ls, 16, 64);
      ls += __shfl_xor(ls, 32, 64);
      lsum[qi] += ls;
      // pack P^T: per j, 4 k-contiguous bf16 (truncated) -> one b64 LDS write
      unsigned char* Pb = (unsigned char*)(Pts[w][qi]);
      #pragma unroll
      for (int j = 0; j < 4; ++j) {
        union { float f; unsigned int u; } c0, c1, c2, c3;
        c0.f = sc[qi][j][0]; c1.f = sc[qi][j][1];
        c2.f = sc[qi][j][2]; c3.f = sc[qi][j][3];
        u32x2 pk;
        pk[0] = __builtin_amdgcn_perm(c1.u, c0.u, 0x07060302u);
        pk[1] = __builtin_amdgcn_perm(c3.u, c2.u, 0x07060302u);
        const int slot = ((j << 1) | (quad >> 1)) ^ (lm & 7);
        *(u32x2*)(Pb + pwbase + (slot << 4)) = pk;
      }
    }
    // PV: V fragments read once, consumed by both q-fragments
    __builtin_amdgcn_s_setprio(1);
    #pragma unroll
    for (int st = 0; st < 2; ++st) {
      const int kc = ((st * 4 + quad) ^ (lm & 7)) * 8;
      short8 vv[4];
      #pragma unroll
      for (int j = 0; j < 4; ++j)
        vv[j] = *(const short8*)(Vts + (j * 16 + lm) * 64 + kc);
      #pragma unroll
      for (int qi = 0; qi < 2; ++qi) {
        short8 pf = *(const short8*)((unsigned char*)(Pts[w][qi]) + prbase +
                                     ((((st << 2) | quad) ^ (lm & 7)) << 4));
        #pragma unroll
        for (int j = 0; j < 4; ++j)
          oacc[qi][j] = __builtin_amdgcn_mfma_f32_16x16x32_bf16(vv[j], pf, oacc[qi][j], 0, 0, 0);
      }
    }
    __builtin_amdgcn_s_setprio(0);
  }
  // epilogue: lane holds O[q=lm][d = j*16 + quad*4 + r] per q-fragment
  #pragma unroll
  for (int qi = 0; qi < 2; ++qi) {
    const float inv = 1.f / lsum[qi];
    const size_t obase = (size_t)b * SS * CC +
        (size_t)(q0 + w * 32 + qi * 16 + lm) * CC + h * 64 + quad * 4;
    #pragma unroll
    for (int j = 0; j < 4; ++j) {
      ushort4v pk;
      #pragma unroll
      for (int r = 0; r < 4; ++r) pk[r] = f2bf(oacc[qi][j][r] * inv);
      *(ushort4v*)(Oh + obase + j * 16) = pk;
    }
  }
}

extern "C" void kernel_launch(void* const* d_in, const int* in_sizes, int n_in,
                              void* d_out, int out_size, void* d_ws, size_t ws_size,
                              hipStream_t stream) {
  const float* x    = (const float*)d_in[0];
  const float* K_W  = (const float*)d_in[2];
  const float* K_b  = (const float*)d_in[3];
  const float* Q_W  = (const float*)d_in[4];
  const float* Q_b  = (const float*)d_in[5];
  const float* V_W  = (const float*)d_in[6];
  const float* V_b  = (const float*)d_in[7];
  const float* O_W  = (const float*)d_in[8];
  const float* O_b  = (const float*)d_in[9];
  const float* ln1g = (const float*)d_in[10];
  const float* ln1b = (const float*)d_in[11];
  const float* ln2g = (const float*)d_in[12];
  const float* ln2b = (const float*)d_in[13];
  const float* W1   = (const float*)d_in[14];
  const float* b1   = (const float*)d_in[15];
  const float* W2   = (const float*)d_in[16];
  const float* b2   = (const float*)d_in[17];
  float* out = (float*)d_out;

  unsigned char* ws = (unsigned char*)d_ws;
  const size_t MB = 1u << 20;
  unsigned short* qkh   = (unsigned short*)(ws);             // (B,S,1024) 16MB
  unsigned short* qkl   = (unsigned short*)(ws + 16 * MB);   // 16MB
  unsigned short* vt    = (unsigned short*)(ws + 32 * MB);   // (B,NH,HD,S) 8MB
  unsigned short* ln1h  = (unsigned short*)(ws + 40 * MB);   // 8MB
  unsigned short* ln1l  = (unsigned short*)(ws + 48 * MB);   // 8MB
  float* xsf            = (float*)(ws + 56 * MB);            // (B,S,C) f32 16MB
  unsigned short* oh    = ln1h;
  float* out1           = (float*)(ws + 72 * MB);            // 16MB
  unsigned short* ln2h  = qkh;
  unsigned short* geluh = (unsigned short*)(ws + 8 * MB);
  unsigned short* BtAll = (unsigned short*)(ws + 88 * MB);
  unsigned short* BtQKh = BtAll;
  unsigned short* BtVh  = BtAll + 1024 * 512;
  unsigned short* BtQKl = BtVh + 512 * 512;
  unsigned short* BtOh  = BtQKl + 1024 * 512;
  unsigned short* BtOl  = BtOh + 512 * 512;
  unsigned short* BtW1h = BtOl + 512 * 512;
  unsigned short* BtW2h = BtW1h + 512 * 512;
  float* qkvb           = (float*)(BtW2h + 512 * 512);
  float2* mustd         = (float2*)(ws + 96 * MB);

  dim3 tb32(32, 8);
  convert_and_stats<<<1536 + 128, 256, 0, stream>>>(
      Q_W, K_W, V_W, O_W, W1, W2, Q_b, K_b, V_b,
      BtQKh, BtQKl, BtVh, BtOh, BtOl, BtW1h, BtW2h, qkvb, x, mustd);
  ln1_apply<<<dim3(SS / 32, CC / 32, BB), tb32, 0, stream>>>(
      x, mustd, ln1g, ln1b, ln1h, ln1l, xsf);
  gemm_qkv<<<768, 256, 0, stream>>>(
      ln1h, ln1l, BtAll, BtQKl, qkvb, qkh, qkl, vt);
  attn_mfma<<<512, 256, 0, stream>>>(qkh, qkl, vt, oh);
  gemm64<1, 0, 0, 1, 0><<<1024, 256, 0, stream>>>(
      oh, BtOh, BtOl, O_b, xsf, nullptr, nullptr, nullptr, out1, CC);
  ln_bf16_k<<<BB * SS / 4, 256, 0, stream>>>(out1, ln2g, ln2b, ln2h);
  gemm64<0, 1, 1, 0, 0><<<1024, 256, 0, stream>>>(
      ln2h, BtW1h, nullptr, b1, nullptr, nullptr, nullptr, geluh, nullptr, CC);
  gemm64<0, 0, 0, 1, 1><<<1024, 256, 0, stream>>>(
      geluh, BtW2h, nullptr, b2, out1, nullptr, nullptr, nullptr, out, CC);
}